// Round 1
// baseline (3504.678 us; speedup 1.0000x reference)
//
#include <hip/hip_runtime.h>
#include <math.h>

#define EPS 1e-5f

__device__ __forceinline__ float mishf(float x) {
    float sp = fmaxf(x, 0.0f) + log1pf(expf(-fabsf(x)));
    return x * tanhf(sp);
}

// ---------------------------------------------------------------- mish(t)
__global__ __launch_bounds__(256) void mish_k(const float* __restrict__ t,
                                              float* __restrict__ mt, int n) {
    int i = blockIdx.x * 256 + threadIdx.x;
    if (i < n) mt[i] = mishf(t[i]);
}

// ------------------------------------------------ generic NT GEMM + bias
// C[r,c] = sum_k A[r,k] * W[c,k] + bias[c];  A: MxKD, W: NxKD, both row-major.
// M, N multiples of 64; KD multiple of 16.
template<int KD>
__global__ __launch_bounds__(256) void gemm_nt(const float* __restrict__ A,
        const float* __restrict__ W, const float* __restrict__ bias,
        float* __restrict__ C, int M, int N) {
    constexpr int ST = 20; // 16 + 4 pad, keeps float4 alignment, 2-way banks
    __shared__ __align__(16) float As[64 * ST];
    __shared__ __align__(16) float Ws[64 * ST];
    const int tid = threadIdx.x;
    const int r0 = blockIdx.x * 64, c0 = blockIdx.y * 64;
    const int tx = tid & 15, ty = tid >> 4;
    const int lrow = tid >> 2, lk = (tid & 3) * 4;
    float acc[4][4];
#pragma unroll
    for (int i = 0; i < 4; ++i)
#pragma unroll
        for (int j = 0; j < 4; ++j) acc[i][j] = 0.f;

    for (int k0 = 0; k0 < KD; k0 += 16) {
        __syncthreads();
        *(float4*)&As[lrow * ST + lk] =
            *(const float4*)&A[(size_t)(r0 + lrow) * KD + k0 + lk];
        *(float4*)&Ws[lrow * ST + lk] =
            *(const float4*)&W[(size_t)(c0 + lrow) * KD + k0 + lk];
        __syncthreads();
#pragma unroll
        for (int kk = 0; kk < 16; kk += 4) {
            float4 av[4], wv[4];
#pragma unroll
            for (int i = 0; i < 4; ++i)
                av[i] = *(const float4*)&As[(ty + 16 * i) * ST + kk];
#pragma unroll
            for (int j = 0; j < 4; ++j)
                wv[j] = *(const float4*)&Ws[(tx + 16 * j) * ST + kk];
#pragma unroll
            for (int i = 0; i < 4; ++i)
#pragma unroll
                for (int j = 0; j < 4; ++j) {
                    acc[i][j] = fmaf(av[i].x, wv[j].x, acc[i][j]);
                    acc[i][j] = fmaf(av[i].y, wv[j].y, acc[i][j]);
                    acc[i][j] = fmaf(av[i].z, wv[j].z, acc[i][j]);
                    acc[i][j] = fmaf(av[i].w, wv[j].w, acc[i][j]);
                }
        }
    }
#pragma unroll
    for (int j = 0; j < 4; ++j) {
        int c = c0 + tx + 16 * j;
        float bv = bias[c];
#pragma unroll
        for (int i = 0; i < 4; ++i) {
            int r = r0 + ty + 16 * i;
            C[(size_t)r * N + c] = acc[i][j] + bv;
        }
    }
}

// ------------------------------------------------------------ 1D conv
// out[b,co,l] = bias[co] + sum_{ci,k} x[b,ci,l+k-PAD] * w[co,ci,k]  (+addend)
// x: B x CI x 512, w: 512 x CI x KS, out: B x 512 x 512
template<int CI, int KS, int PAD, bool ADD>
__global__ __launch_bounds__(256) void conv1d_k(const float* __restrict__ x,
        const float* __restrict__ w, const float* __restrict__ bias,
        const float* __restrict__ addend, float* __restrict__ out) {
    constexpr int LT = 128, COT = 32, CICH = 16;
    constexpr int ROW = LT + KS - 1;
    constexpr int XST = (ROW + 3) & ~3;      // 132 (KS=5) / 128 (KS=1)
    constexpr int WST = CICH * KS + 1;       // 81 / 17 (pad kills bank conflict)
    constexpr int XV = 8 + KS - 1;           // 12 / 8
    static_assert(XV % 4 == 0, "xv must be float4-multiple");
    __shared__ __align__(16) float xs[CICH * XST];
    __shared__ float wsm[COT * WST];

    const int tid = threadIdx.x;
    const int l0 = blockIdx.x * LT;
    const int co0 = blockIdx.y * COT;
    const int b = blockIdx.z;
    const int tl = tid & 15;   // l-octet index
    const int cog = tid >> 4;  // 0..15 -> 2 co each

    float acc[2][8];
#pragma unroll
    for (int u = 0; u < 2; ++u)
#pragma unroll
        for (int j = 0; j < 8; ++j) acc[u][j] = 0.f;

    for (int ci0 = 0; ci0 < CI; ci0 += CICH) {
        __syncthreads();
        for (int idx = tid; idx < CICH * ROW; idx += 256) {
            int cr = idx / ROW, p = idx - cr * ROW;
            int gl = l0 - PAD + p;
            float v = 0.f;
            if (gl >= 0 && gl < 512)
                v = x[((size_t)b * CI + ci0 + cr) * 512 + gl];
            xs[cr * XST + p] = v;
        }
        for (int idx = tid; idx < COT * CICH * KS; idx += 256) {
            int cr = idx / (CICH * KS), rem = idx - cr * (CICH * KS);
            wsm[cr * WST + rem] =
                w[(size_t)(co0 + cr) * (CI * KS) + ci0 * KS + rem];
        }
        __syncthreads();
#pragma unroll 4
        for (int ci = 0; ci < CICH; ++ci) {
            float xv[XV];
            const float* xrow = &xs[ci * XST + tl * 8];
#pragma unroll
            for (int q4 = 0; q4 < XV / 4; ++q4) {
                float4 f = *(const float4*)(xrow + q4 * 4);
                xv[q4 * 4 + 0] = f.x; xv[q4 * 4 + 1] = f.y;
                xv[q4 * 4 + 2] = f.z; xv[q4 * 4 + 3] = f.w;
            }
#pragma unroll
            for (int u = 0; u < 2; ++u) {
                const float* wrow = &wsm[(cog * 2 + u) * WST + ci * KS];
#pragma unroll
                for (int k = 0; k < KS; ++k) {
                    float wv = wrow[k];
#pragma unroll
                    for (int j = 0; j < 8; ++j)
                        acc[u][j] = fmaf(xv[j + k], wv, acc[u][j]);
                }
            }
        }
    }
#pragma unroll
    for (int u = 0; u < 2; ++u) {
        const int co = co0 + cog * 2 + u;
        const float bv = bias[co];
        const size_t base = ((size_t)b * 512 + co) * 512 + l0 + tl * 8;
        float r[8];
#pragma unroll
        for (int j = 0; j < 8; ++j) r[j] = acc[u][j] + bv;
        if (ADD) {
            float4 a0 = *(const float4*)&addend[base];
            float4 a1 = *(const float4*)&addend[base + 4];
            r[0] += a0.x; r[1] += a0.y; r[2] += a0.z; r[3] += a0.w;
            r[4] += a1.x; r[5] += a1.y; r[6] += a1.z; r[7] += a1.w;
        }
        float4 o0 = {r[0], r[1], r[2], r[3]};
        float4 o1 = {r[4], r[5], r[6], r[7]};
        *(float4*)&out[base] = o0;
        *(float4*)&out[base + 4] = o1;
    }
}

// ----------------------------------- per-step GroupNorm (+FiLM) + mish, in place
// h: B x 512 x 512. stats over 64 channels per (b, group, l).
template<bool FILM>
__global__ __launch_bounds__(256) void gn_k(float* __restrict__ h,
        const float* __restrict__ gam, const float* __restrict__ bet,
        const float* __restrict__ ss) {
    __shared__ float tile[64 * 65];
    __shared__ float ps[4 * 64], ps2[4 * 64];
    __shared__ float mean_s[64], rstd_s[64];
    const int tid = threadIdx.x;
    const int l0 = blockIdx.x * 64, b = blockIdx.y;
    const int ll = tid & 63, cq = tid >> 6;
    for (int g = 0; g < 8; ++g) {
        __syncthreads();
        for (int idx = tid; idx < 64 * 64; idx += 256) {
            int cr = idx >> 6, p = idx & 63;
            tile[cr * 65 + p] = h[((size_t)b * 512 + g * 64 + cr) * 512 + l0 + p];
        }
        __syncthreads();
        float s = 0.f, s2 = 0.f;
#pragma unroll
        for (int i = 0; i < 16; ++i) {
            float val = tile[(cq * 16 + i) * 65 + ll];
            s += val; s2 += val * val;
        }
        ps[cq * 64 + ll] = s; ps2[cq * 64 + ll] = s2;
        __syncthreads();
        if (tid < 64) {
            float ts = ps[tid] + ps[64 + tid] + ps[128 + tid] + ps[192 + tid];
            float ts2 = ps2[tid] + ps2[64 + tid] + ps2[128 + tid] + ps2[192 + tid];
            float m = ts * (1.f / 64.f);
            float var = ts2 * (1.f / 64.f) - m * m;
            mean_s[tid] = m;
            rstd_s[tid] = rsqrtf(var + EPS);
        }
        __syncthreads();
        float m = mean_s[ll], rs = rstd_s[ll];
#pragma unroll
        for (int i = 0; i < 16; ++i) {
            int c = g * 64 + cq * 16 + i;
            float val = (tile[(cq * 16 + i) * 65 + ll] - m) * rs * gam[c] + bet[c];
            if (FILM)
                val = val * (1.f + ss[(size_t)b * 1024 + c]) + ss[(size_t)b * 1024 + 512 + c];
            val = mishf(val);
            h[((size_t)b * 512 + c) * 512 + l0 + ll] = val;
        }
    }
}

// --------- LayerNorm over channels of out[cidx[b]] + transpose -> xt[b,t,c]
__global__ __launch_bounds__(256) void lnt_k(const float* __restrict__ src,
        const float* __restrict__ g, const float* __restrict__ be,
        const int* __restrict__ cidx, float* __restrict__ xt) {
    __shared__ float tile[64 * 65];
    __shared__ float ps[4 * 64], ps2[4 * 64];
    __shared__ float mean_s[64], rstd_s[64];
    const int tid = threadIdx.x;
    const int l0 = blockIdx.x * 64, b = blockIdx.y;
    const int ib = cidx[b];
    const int ll = tid & 63, cq = tid >> 6;
    float s = 0.f, s2 = 0.f;
    for (int i = 0; i < 128; ++i) {
        int c = cq * 128 + i;
        float v = src[((size_t)ib * 512 + c) * 512 + l0 + ll];
        s += v; s2 += v * v;
    }
    ps[cq * 64 + ll] = s; ps2[cq * 64 + ll] = s2;
    __syncthreads();
    if (tid < 64) {
        float ts = ps[tid] + ps[64 + tid] + ps[128 + tid] + ps[192 + tid];
        float ts2 = ps2[tid] + ps2[64 + tid] + ps2[128 + tid] + ps2[192 + tid];
        float m = ts * (1.f / 512.f);
        float var = ts2 * (1.f / 512.f) - m * m;
        mean_s[tid] = m;
        rstd_s[tid] = rsqrtf(var + EPS);
    }
    const int cc = tid & 63, tq = tid >> 6;
    for (int cg = 0; cg < 8; ++cg) {
        __syncthreads();
        for (int idx = tid; idx < 64 * 64; idx += 256) {
            int cr = idx >> 6, p = idx & 63;
            tile[cr * 65 + p] = src[((size_t)ib * 512 + cg * 64 + cr) * 512 + l0 + p];
        }
        __syncthreads();
        float gg = g[cg * 64 + cc], bb = be[cg * 64 + cc];
#pragma unroll
        for (int i = 0; i < 16; ++i) {
            int tt = tq * 16 + i;
            float v = (tile[cc * 65 + tt] - mean_s[tt]) * rstd_s[tt] * gg + bb;
            xt[((size_t)b * 512 + l0 + tt) * 512 + cg * 64 + cc] = v;
        }
    }
}

// --------------- q softmax over Dh=64 (one wave per head group), in place
__global__ __launch_bounds__(512) void qsm_k(float* __restrict__ q) {
    const size_t base = (size_t)blockIdx.x * 512;
    const int d = threadIdx.x;
    float v = q[base + d];
    float mx = v;
#pragma unroll
    for (int o = 32; o > 0; o >>= 1) mx = fmaxf(mx, __shfl_xor(mx, o, 64));
    float e = expf(v - mx);
    float s = e;
#pragma unroll
    for (int o = 32; o > 0; o >>= 1) s += __shfl_xor(s, o, 64);
    q[base + d] = e / s;
}

// --------------------------- LayerNorm of cond rows (768) -> cn[b,n,:]
__global__ __launch_bounds__(256) void lnc_k(const float* __restrict__ cond,
        const float* __restrict__ g, const float* __restrict__ be,
        const int* __restrict__ cidx, float* __restrict__ cn) {
    const int tid = threadIdx.x;
    const int bn = blockIdx.x;
    const int b = bn / 77, n = bn - b * 77;
    const int ib = cidx[b];
    const float* src = cond + ((size_t)ib * 77 + n) * 768;
    float v[3];
    float s = 0.f, s2 = 0.f;
#pragma unroll
    for (int i = 0; i < 3; ++i) {
        v[i] = src[tid + i * 256];
        s += v[i]; s2 += v[i] * v[i];
    }
#pragma unroll
    for (int o = 32; o > 0; o >>= 1) {
        s += __shfl_xor(s, o, 64);
        s2 += __shfl_xor(s2, o, 64);
    }
    __shared__ float r1[4], r2[4], mv[2];
    if ((tid & 63) == 0) { r1[tid >> 6] = s; r2[tid >> 6] = s2; }
    __syncthreads();
    if (tid == 0) {
        float ts = r1[0] + r1[1] + r1[2] + r1[3];
        float ts2 = r2[0] + r2[1] + r2[2] + r2[3];
        float m = ts * (1.f / 768.f);
        float var = ts2 * (1.f / 768.f) - m * m;
        mv[0] = m; mv[1] = rsqrtf(var + EPS);
    }
    __syncthreads();
    float m = mv[0], rs = mv[1];
    float* dst = cn + ((size_t)b * 77 + n) * 768;
#pragma unroll
    for (int i = 0; i < 3; ++i) {
        int c = tid + i * 256;
        dst[c] = (v[i] - m) * rs * g[c] + be[c];
    }
}

// ----------------------- k softmax over N=77 per (b, d=h*64+dh), in place
__global__ __launch_bounds__(256) void ksm_k(float* __restrict__ k) {
    int gid = blockIdx.x * 256 + threadIdx.x; // 0..32767
    int b = gid >> 9, d = gid & 511;
    float* p = k + (size_t)b * 77 * 512 + d;
    float mx = -3.4e38f;
    for (int n = 0; n < 77; ++n) mx = fmaxf(mx, p[(size_t)n * 512]);
    float s = 0.f;
    for (int n = 0; n < 77; ++n) s += expf(p[(size_t)n * 512] - mx);
    float inv = 1.f / s;
    for (int n = 0; n < 77; ++n)
        p[(size_t)n * 512] = expf(p[(size_t)n * 512] - mx) * inv;
}

// ------------------- attn[b,h,d,e] = sum_n k[b,n,h*64+d] * v[b,n,h*64+e]
__global__ __launch_bounds__(256) void attn_k(const float* __restrict__ k,
        const float* __restrict__ v, float* __restrict__ attn) {
    constexpr int NS = 68;
    __shared__ __align__(16) float ks[77 * NS];
    __shared__ __align__(16) float vs[77 * NS];
    const int tid = threadIdx.x;
    const int b = blockIdx.x >> 3, h = blockIdx.x & 7;
    for (int idx = tid; idx < 77 * 16; idx += 256) {
        int n = idx >> 4, dq = (idx & 15) * 4;
        *(float4*)&ks[n * NS + dq] =
            *(const float4*)&k[((size_t)b * 77 + n) * 512 + h * 64 + dq];
        *(float4*)&vs[n * NS + dq] =
            *(const float4*)&v[((size_t)b * 77 + n) * 512 + h * 64 + dq];
    }
    __syncthreads();
    const int e = tid & 63, dq = tid >> 6;
    float acc[16];
#pragma unroll
    for (int u = 0; u < 16; ++u) acc[u] = 0.f;
    for (int n = 0; n < 77; ++n) {
        float vv = vs[n * NS + e];
#pragma unroll
        for (int u4 = 0; u4 < 4; ++u4) {
            float4 kk = *(const float4*)&ks[n * NS + dq * 16 + u4 * 4];
            acc[u4 * 4 + 0] = fmaf(kk.x, vv, acc[u4 * 4 + 0]);
            acc[u4 * 4 + 1] = fmaf(kk.y, vv, acc[u4 * 4 + 1]);
            acc[u4 * 4 + 2] = fmaf(kk.z, vv, acc[u4 * 4 + 2]);
            acc[u4 * 4 + 3] = fmaf(kk.w, vv, acc[u4 * 4 + 3]);
        }
    }
#pragma unroll
    for (int u = 0; u < 16; ++u)
        attn[(((size_t)b * 8 + h) * 64 + dq * 16 + u) * 64 + e] = acc[u];
}

// -------- out[cidx[b], h*64+e, t] += sum_d q[b,t,h*64+d] * attn[b,h,d,e]
__global__ __launch_bounds__(256) void yattn_k(const float* __restrict__ q,
        const float* __restrict__ attn, const int* __restrict__ cidx,
        float* __restrict__ out) {
    __shared__ float qs[64 * 65];
    __shared__ __align__(16) float as_[64 * 68];
    const int tid = threadIdx.x;
    const int t0 = blockIdx.x * 64, h = blockIdx.y, b = blockIdx.z;
    const int ib = cidx[b];
    for (int idx = tid; idx < 64 * 64; idx += 256) {
        int r = idx >> 6, cpos = idx & 63;
        qs[r * 65 + cpos] = q[((size_t)b * 512 + t0 + r) * 512 + h * 64 + cpos];
        as_[r * 68 + cpos] = attn[(((size_t)b * 8 + h) * 64 + r) * 64 + cpos];
    }
    __syncthreads();
    const int tl = tid & 63, eq = tid >> 6;
    float acc[16];
#pragma unroll
    for (int u = 0; u < 16; ++u) acc[u] = 0.f;
#pragma unroll 8
    for (int d = 0; d < 64; ++d) {
        float qv = qs[tl * 65 + d];
#pragma unroll
        for (int u4 = 0; u4 < 4; ++u4) {
            float4 aa = *(const float4*)&as_[d * 68 + eq * 16 + u4 * 4];
            acc[u4 * 4 + 0] = fmaf(qv, aa.x, acc[u4 * 4 + 0]);
            acc[u4 * 4 + 1] = fmaf(qv, aa.y, acc[u4 * 4 + 1]);
            acc[u4 * 4 + 2] = fmaf(qv, aa.z, acc[u4 * 4 + 2]);
            acc[u4 * 4 + 3] = fmaf(qv, aa.w, acc[u4 * 4 + 3]);
        }
    }
#pragma unroll
    for (int u = 0; u < 16; ++u)
        atomicAdd(&out[((size_t)ib * 512 + h * 64 + eq * 16 + u) * 512 + t0 + tl],
                  acc[u]);
}

extern "C" void kernel_launch(void* const* d_in, const int* in_sizes, int n_in,
                              void* d_out, int out_size, void* d_ws, size_t ws_size,
                              hipStream_t stream) {
    (void)in_sizes; (void)n_in; (void)out_size; (void)ws_size;
    const float* x       = (const float*)d_in[0];
    const float* t       = (const float*)d_in[1];
    const float* cond    = (const float*)d_in[2];
    const float* conv0_w = (const float*)d_in[3];
    const float* conv0_b = (const float*)d_in[4];
    const float* gn0_g   = (const float*)d_in[5];
    const float* gn0_b   = (const float*)d_in[6];
    const float* tm_w    = (const float*)d_in[7];
    const float* tm_b    = (const float*)d_in[8];
    const float* conv1_w = (const float*)d_in[9];
    const float* conv1_b = (const float*)d_in[10];
    const float* gn1_g   = (const float*)d_in[11];
    const float* gn1_b   = (const float*)d_in[12];
    const float* res_w   = (const float*)d_in[13];
    const float* res_b   = (const float*)d_in[14];
    const float* ln_x_g  = (const float*)d_in[15];
    const float* ln_x_b  = (const float*)d_in[16];
    const float* ln_c_g  = (const float*)d_in[17];
    const float* ln_c_b  = (const float*)d_in[18];
    const float* q_w     = (const float*)d_in[19];
    const float* q_b     = (const float*)d_in[20];
    const float* k_w     = (const float*)d_in[21];
    const float* k_b     = (const float*)d_in[22];
    const float* v_w     = (const float*)d_in[23];
    const float* v_b     = (const float*)d_in[24];
    const int*   cidx    = (const int*)d_in[25];
    float* out = (float*)d_out;

    float* ws   = (float*)d_ws;
    float* ssb  = ws;                      // 64*1024
    float* mt   = ssb + 65536;             // 64*512
    float* bufA = mt + 32768;              // 64*512*512
    float* bufB = bufA + 16777216;         // 64*512*512
    // overlays on bufA, alive only after qproj consumed xt:
    float* cn = bufA;                      // 64*77*768
    float* kb = bufA + 3784704;            // 64*77*512
    float* vb = kb + 2523136;              // 64*77*512
    float* ab = vb + 2523136;              // 64*8*64*64

    // 1) ss = mish(t) @ tm_w^T + tm_b
    mish_k<<<dim3(128), dim3(256), 0, stream>>>(t, mt, 32768);
    gemm_nt<512><<<dim3(1, 16), dim3(256), 0, stream>>>(mt, tm_w, tm_b, ssb, 64, 1024);
    // 2) conv0 -> bufA, then per-step GN + FiLM + mish in place
    conv1d_k<256, 5, 2, false><<<dim3(4, 16, 64), dim3(256), 0, stream>>>(
        x, conv0_w, conv0_b, (const float*)nullptr, bufA);
    gn_k<true><<<dim3(8, 64), dim3(256), 0, stream>>>(bufA, gn0_g, gn0_b, ssb);
    // 3) conv1 -> bufB, then GN + mish in place
    conv1d_k<512, 5, 2, false><<<dim3(4, 16, 64), dim3(256), 0, stream>>>(
        bufA, conv1_w, conv1_b, (const float*)nullptr, bufB);
    gn_k<false><<<dim3(8, 64), dim3(256), 0, stream>>>(bufB, gn1_g, gn1_b,
                                                       (const float*)nullptr);
    // 4) out = bufB + res_conv(x)
    conv1d_k<256, 1, 0, true><<<dim3(4, 16, 64), dim3(256), 0, stream>>>(
        x, res_w, res_b, bufB, out);
    // 5) xt = LN_channels(out[cidx]) transposed to (b,t,c) -> bufA
    lnt_k<<<dim3(8, 64), dim3(256), 0, stream>>>(out, ln_x_g, ln_x_b, cidx, bufA);
    // 6) q = xt @ q_w^T + q_b -> bufB ; softmax over Dh
    gemm_nt<512><<<dim3(512, 8), dim3(256), 0, stream>>>(bufA, q_w, q_b, bufB,
                                                         32768, 512);
    qsm_k<<<dim3(32768), dim3(512), 0, stream>>>(bufB);
    // 7) cn = LN(cond[cidx]); k,v projections; k softmax over N
    lnc_k<<<dim3(4928), dim3(256), 0, stream>>>(cond, ln_c_g, ln_c_b, cidx, cn);
    gemm_nt<768><<<dim3(77, 8), dim3(256), 0, stream>>>(cn, k_w, k_b, kb, 4928, 512);
    gemm_nt<768><<<dim3(77, 8), dim3(256), 0, stream>>>(cn, v_w, v_b, vb, 4928, 512);
    ksm_k<<<dim3(128), dim3(256), 0, stream>>>(kb);
    // 8) attn = k^T v per (b,h); y = q @ attn scattered into out
    attn_k<<<dim3(512), dim3(256), 0, stream>>>(kb, vb, ab);
    yattn_k<<<dim3(8, 8, 64), dim3(256), 0, stream>>>(bufB, ab, cidx, out);
}

// Round 2
// 1090.617 us; speedup vs baseline: 3.2135x; 3.2135x over previous
//
#include <hip/hip_runtime.h>
#include <math.h>

#define EPS 1e-5f

typedef __attribute__((ext_vector_type(8))) short short8;
typedef __attribute__((ext_vector_type(4))) float floatx4;

__device__ __forceinline__ float mishf(float x) {
    float sp = fmaxf(x, 0.0f) + log1pf(expf(-fabsf(x)));
    return x * tanhf(sp);
}
__device__ __forceinline__ unsigned short f2bf(float f) {
    unsigned int u = __float_as_uint(f);
    unsigned int r = (u + 0x7fffu + ((u >> 16) & 1u)) >> 16;
    return (unsigned short)r;
}
__device__ __forceinline__ float bf2f(unsigned short s) {
    return __uint_as_float(((unsigned int)s) << 16);
}

// ---------------------------------------------------------------- mish(t)
__global__ __launch_bounds__(256) void mish_k(const float* __restrict__ t,
                                              float* __restrict__ mt, int n) {
    int i = blockIdx.x * 256 + threadIdx.x;
    if (i < n) mt[i] = mishf(t[i]);
}

// ------------------------------------------------- weight pack fp32->bf16
// wp[(kk*512 + co)*CI + ci] = bf16( w[(co*CI + ci)*KS + kk] )
__global__ __launch_bounds__(256) void pack_w(const float* __restrict__ w,
        unsigned short* __restrict__ wp, int CI, int KS, int n) {
    int o = blockIdx.x * 256 + threadIdx.x;
    if (o >= n) return;
    int ci = o % CI;
    int co = (o / CI) & 511;
    int kk = o / (CI * 512);
    wp[o] = f2bf(w[((size_t)co * CI + ci) * KS + kk]);
}

// ------------------------------------------------------- fp32 -> bf16 copy
__global__ __launch_bounds__(256) void cvt_bf16(const float* __restrict__ src,
        unsigned short* __restrict__ dst, int n4) {
    int i = blockIdx.x * 256 + threadIdx.x;
    if (i >= n4) return;
    float4 f = *(const float4*)&src[(size_t)i * 4];
    unsigned int lo = f2bf(f.x) | ((unsigned int)f2bf(f.y) << 16);
    unsigned int hi = f2bf(f.z) | ((unsigned int)f2bf(f.w) << 16);
    *(uint2*)&dst[(size_t)i * 4] = make_uint2(lo, hi);
}

// ------------------------------------------------ generic NT GEMM + bias (fp32)
template<int KD>
__global__ __launch_bounds__(256) void gemm_nt(const float* __restrict__ A,
        const float* __restrict__ W, const float* __restrict__ bias,
        float* __restrict__ C, int M, int N) {
    constexpr int ST = 20;
    __shared__ __align__(16) float As[64 * ST];
    __shared__ __align__(16) float Ws[64 * ST];
    const int tid = threadIdx.x;
    const int r0 = blockIdx.x * 64, c0 = blockIdx.y * 64;
    const int tx = tid & 15, ty = tid >> 4;
    const int lrow = tid >> 2, lk = (tid & 3) * 4;
    float acc[4][4];
#pragma unroll
    for (int i = 0; i < 4; ++i)
#pragma unroll
        for (int j = 0; j < 4; ++j) acc[i][j] = 0.f;

    for (int k0 = 0; k0 < KD; k0 += 16) {
        __syncthreads();
        *(float4*)&As[lrow * ST + lk] =
            *(const float4*)&A[(size_t)(r0 + lrow) * KD + k0 + lk];
        *(float4*)&Ws[lrow * ST + lk] =
            *(const float4*)&W[(size_t)(c0 + lrow) * KD + k0 + lk];
        __syncthreads();
#pragma unroll
        for (int kk = 0; kk < 16; kk += 4) {
            float4 av[4], wv[4];
#pragma unroll
            for (int i = 0; i < 4; ++i)
                av[i] = *(const float4*)&As[(ty + 16 * i) * ST + kk];
#pragma unroll
            for (int j = 0; j < 4; ++j)
                wv[j] = *(const float4*)&Ws[(tx + 16 * j) * ST + kk];
#pragma unroll
            for (int i = 0; i < 4; ++i)
#pragma unroll
                for (int j = 0; j < 4; ++j) {
                    acc[i][j] = fmaf(av[i].x, wv[j].x, acc[i][j]);
                    acc[i][j] = fmaf(av[i].y, wv[j].y, acc[i][j]);
                    acc[i][j] = fmaf(av[i].z, wv[j].z, acc[i][j]);
                    acc[i][j] = fmaf(av[i].w, wv[j].w, acc[i][j]);
                }
        }
    }
#pragma unroll
    for (int j = 0; j < 4; ++j) {
        int c = c0 + tx + 16 * j;
        float bv = bias[c];
#pragma unroll
        for (int i = 0; i < 4; ++i) {
            int r = r0 + ty + 16 * i;
            C[(size_t)r * N + c] = acc[i][j] + bv;
        }
    }
}

// ------------------------------------------------- MFMA bf16 implicit-GEMM conv1d
// x: [64][CI][512] bf16, wp: [KS][512][CI] bf16 (packed), out: [64][512][512]
// Block: 64 co x 256 l, 4 waves (each 64co x 64l quadrant in l), K-chunks of 32 ci.
template<int CI, int KS, bool BF16OUT, bool ADD>
__global__ __launch_bounds__(256) void conv_mfma(
        const unsigned short* __restrict__ xb,
        const unsigned short* __restrict__ wp,
        const float* __restrict__ bias,
        const unsigned short* __restrict__ addend,
        void* __restrict__ outp) {
    static_assert(CI % 32 == 0, "CI%32");
    constexpr int LT = 256;
    constexpr int PAD = (KS - 1) / 2;
    constexpr int ROWS = LT + KS - 1;
    constexpr int XS = 40;              // xs row stride (bf16): 80B, 16B-aligned rows
    constexpr int WROW = KS * 32 + 8;   // ws row stride: 336B (KS=5)/80B (KS=1)
    __shared__ __align__(16) unsigned short xs[ROWS * XS];
    __shared__ __align__(16) unsigned short ws[64 * WROW];

    const int tid = threadIdx.x;
    const int l0 = blockIdx.x * LT;
    const int co0 = blockIdx.y * 64;
    const int b = blockIdx.z;
    const int lane = tid & 63;
    const int wv = tid >> 6;
    const int lq = lane & 15;
    const int qd = lane >> 4;
    const int wn = wv * 64;

    floatx4 acc[4][4];
#pragma unroll
    for (int i = 0; i < 4; ++i)
#pragma unroll
        for (int j = 0; j < 4; ++j) acc[i][j] = (floatx4){0.f, 0.f, 0.f, 0.f};

    for (int ci0 = 0; ci0 < CI; ci0 += 32) {
        __syncthreads();
        // ---- stage X transposed: xs[l_local][ci_local], bf16x2-packed writes
        {
            int task = tid;
#pragma unroll
            for (int it = 0; it < 2; ++it, task += 256) {
                int p = task & 15, g = task >> 4;  // ci pair, l-octet
                const unsigned short* s0 =
                    &xb[((size_t)b * CI + ci0 + 2 * p) * 512 + l0 + g * 8];
                uint4 u0 = *(const uint4*)s0;
                uint4 u1 = *(const uint4*)(s0 + 512);
                unsigned int lo[4] = {u0.x, u0.y, u0.z, u0.w};
                unsigned int hi[4] = {u1.x, u1.y, u1.z, u1.w};
                int rbase = PAD + g * 8;
#pragma unroll
                for (int q = 0; q < 4; ++q) {
                    unsigned int a = lo[q], c = hi[q];
                    unsigned int w0 = (a & 0xffffu) | (c << 16);
                    unsigned int w1 = (a >> 16) | (c & 0xffff0000u);
                    *(unsigned int*)&xs[(rbase + 2 * q) * XS + 2 * p] = w0;
                    *(unsigned int*)&xs[(rbase + 2 * q + 1) * XS + 2 * p] = w1;
                }
            }
        }
        if (KS > 1 && tid < 128) {  // halo rows (l0-2,l0-1,l0+256,l0+257)
            int rh = tid >> 5;
            int r = (rh < 2) ? rh : (LT + rh);
            int ci_l = tid & 31;
            int gl = l0 - PAD + r;
            unsigned short v = 0;
            if (gl >= 0 && gl < 512)
                v = xb[((size_t)b * CI + ci0 + ci_l) * 512 + gl];
            xs[r * XS + ci_l] = v;
        }
        // ---- stage W: ws[co_l][kk*32 + ci_l]
        for (int s = tid; s < 256 * KS; s += 256) {
            int q = s & 3, co_l = (s >> 2) & 63, kk = s >> 8;
            uint4 u = *(const uint4*)
                &wp[((size_t)(kk * 512 + co0 + co_l)) * CI + ci0 + q * 8];
            *(uint4*)&ws[co_l * WROW + kk * 32 + q * 8] = u;
        }
        __syncthreads();
#pragma unroll
        for (int kk = 0; kk < KS; ++kk) {
            short8 bvf[4];
#pragma unroll
            for (int j = 0; j < 4; ++j)
                bvf[j] = *(const short8*)&xs[(wn + j * 16 + lq + kk) * XS + qd * 8];
#pragma unroll
            for (int i = 0; i < 4; ++i) {
                short8 av = *(const short8*)&ws[(i * 16 + lq) * WROW + kk * 32 + qd * 8];
#pragma unroll
                for (int j = 0; j < 4; ++j)
                    acc[i][j] = __builtin_amdgcn_mfma_f32_16x16x32_bf16(
                        av, bvf[j], acc[i][j], 0, 0, 0);
            }
        }
    }
    // ---- epilogue: D row=(lane>>4)*4+reg -> co, col=lane&15 -> l
#pragma unroll
    for (int i = 0; i < 4; ++i) {
#pragma unroll
        for (int r = 0; r < 4; ++r) {
            int co = co0 + i * 16 + qd * 4 + r;
            float bvv = bias[co];
#pragma unroll
            for (int j = 0; j < 4; ++j) {
                int l = l0 + wn + j * 16 + lq;
                size_t oidx = ((size_t)b * 512 + co) * 512 + l;
                float val = acc[i][j][r] + bvv;
                if (ADD) val += bf2f(addend[oidx]);
                if (BF16OUT) ((unsigned short*)outp)[oidx] = f2bf(val);
                else ((float*)outp)[oidx] = val;
            }
        }
    }
}

// ------------------- per-step GroupNorm (+FiLM) + mish, bf16 in/out in place
template<bool FILM>
__global__ __launch_bounds__(256) void gn_bf(unsigned short* __restrict__ h,
        const float* __restrict__ gam, const float* __restrict__ bet,
        const float* __restrict__ ss) {
    __shared__ float tile[64 * 65];
    __shared__ float ps[4 * 64], ps2[4 * 64];
    __shared__ float mean_s[64], rstd_s[64];
    const int tid = threadIdx.x;
    const int l0 = blockIdx.x * 64, b = blockIdx.y;
    const int ll = tid & 63, cq = tid >> 6;
    for (int g = 0; g < 8; ++g) {
        __syncthreads();
        for (int idx = tid; idx < 64 * 64; idx += 256) {
            int cr = idx >> 6, p = idx & 63;
            tile[cr * 65 + p] =
                bf2f(h[((size_t)b * 512 + g * 64 + cr) * 512 + l0 + p]);
        }
        __syncthreads();
        float s = 0.f, s2 = 0.f;
#pragma unroll
        for (int i = 0; i < 16; ++i) {
            float val = tile[(cq * 16 + i) * 65 + ll];
            s += val; s2 += val * val;
        }
        ps[cq * 64 + ll] = s; ps2[cq * 64 + ll] = s2;
        __syncthreads();
        if (tid < 64) {
            float ts = ps[tid] + ps[64 + tid] + ps[128 + tid] + ps[192 + tid];
            float ts2 = ps2[tid] + ps2[64 + tid] + ps2[128 + tid] + ps2[192 + tid];
            float m = ts * (1.f / 64.f);
            float var = ts2 * (1.f / 64.f) - m * m;
            mean_s[tid] = m;
            rstd_s[tid] = rsqrtf(var + EPS);
        }
        __syncthreads();
        float m = mean_s[ll], rs = rstd_s[ll];
#pragma unroll
        for (int i = 0; i < 16; ++i) {
            int c = g * 64 + cq * 16 + i;
            float val = (tile[(cq * 16 + i) * 65 + ll] - m) * rs * gam[c] + bet[c];
            if (FILM)
                val = val * (1.f + ss[(size_t)b * 1024 + c]) + ss[(size_t)b * 1024 + 512 + c];
            val = mishf(val);
            h[((size_t)b * 512 + c) * 512 + l0 + ll] = f2bf(val);
        }
    }
}

// ------- LN over channels of out[cidx[b]] -> xln bf16, SAME [b][c][l] layout
__global__ __launch_bounds__(256) void lnx_k(const float* __restrict__ src,
        const float* __restrict__ g, const float* __restrict__ be,
        const int* __restrict__ cidx, unsigned short* __restrict__ xln) {
    __shared__ float ps[4 * 64], ps2[4 * 64];
    __shared__ float mean_s[64], rstd_s[64];
    const int tid = threadIdx.x;
    const int l0 = blockIdx.x * 64, b = blockIdx.y;
    const int ib = cidx[b];
    const int ll = tid & 63, cq = tid >> 6;
    float s = 0.f, s2 = 0.f;
    for (int i = 0; i < 128; ++i) {
        int c = cq * 128 + i;
        float v = src[((size_t)ib * 512 + c) * 512 + l0 + ll];
        s += v; s2 += v * v;
    }
    ps[cq * 64 + ll] = s; ps2[cq * 64 + ll] = s2;
    __syncthreads();
    if (tid < 64) {
        float ts = ps[tid] + ps[64 + tid] + ps[128 + tid] + ps[192 + tid];
        float ts2 = ps2[tid] + ps2[64 + tid] + ps2[128 + tid] + ps2[192 + tid];
        float m = ts * (1.f / 512.f);
        float var = ts2 * (1.f / 512.f) - m * m;
        mean_s[tid] = m;
        rstd_s[tid] = rsqrtf(var + EPS);
    }
    __syncthreads();
    float m = mean_s[ll], rs = rstd_s[ll];
    for (int i = 0; i < 128; ++i) {
        int c = cq * 128 + i;
        float v = src[((size_t)ib * 512 + c) * 512 + l0 + ll];
        v = (v - m) * rs * g[c] + be[c];
        xln[((size_t)b * 512 + c) * 512 + l0 + ll] = f2bf(v);
    }
}

// ---- q softmax over Dh=64 for layout q[b][d][t]; one thread per (b,h,t)
__global__ __launch_bounds__(256) void qsm2_k(float* __restrict__ q) {
    const int bx = blockIdx.x;
    const int b = bx >> 4, h = (bx >> 1) & 7, th = bx & 1;
    const int t = th * 256 + threadIdx.x;
    float* p = q + ((size_t)b * 512 + h * 64) * 512 + t;
    float v[64];
    float mx = -3.4e38f;
#pragma unroll
    for (int d = 0; d < 64; ++d) {
        v[d] = p[(size_t)d * 512];
        mx = fmaxf(mx, v[d]);
    }
    float s = 0.f;
#pragma unroll
    for (int d = 0; d < 64; ++d) {
        v[d] = expf(v[d] - mx);
        s += v[d];
    }
    float inv = 1.f / s;
#pragma unroll
    for (int d = 0; d < 64; ++d) p[(size_t)d * 512] = v[d] * inv;
}

// --------------------------- LayerNorm of cond rows (768) -> cn[b,n,:]
__global__ __launch_bounds__(256) void lnc_k(const float* __restrict__ cond,
        const float* __restrict__ g, const float* __restrict__ be,
        const int* __restrict__ cidx, float* __restrict__ cn) {
    const int tid = threadIdx.x;
    const int bn = blockIdx.x;
    const int b = bn / 77, n = bn - b * 77;
    const int ib = cidx[b];
    const float* src = cond + ((size_t)ib * 77 + n) * 768;
    float v[3];
    float s = 0.f, s2 = 0.f;
#pragma unroll
    for (int i = 0; i < 3; ++i) {
        v[i] = src[tid + i * 256];
        s += v[i]; s2 += v[i] * v[i];
    }
#pragma unroll
    for (int o = 32; o > 0; o >>= 1) {
        s += __shfl_xor(s, o, 64);
        s2 += __shfl_xor(s2, o, 64);
    }
    __shared__ float r1[4], r2[4], mv[2];
    if ((tid & 63) == 0) { r1[tid >> 6] = s; r2[tid >> 6] = s2; }
    __syncthreads();
    if (tid == 0) {
        float ts = r1[0] + r1[1] + r1[2] + r1[3];
        float ts2 = r2[0] + r2[1] + r2[2] + r2[3];
        float m = ts * (1.f / 768.f);
        float var = ts2 * (1.f / 768.f) - m * m;
        mv[0] = m; mv[1] = rsqrtf(var + EPS);
    }
    __syncthreads();
    float m = mv[0], rs = mv[1];
    float* dst = cn + ((size_t)b * 77 + n) * 768;
#pragma unroll
    for (int i = 0; i < 3; ++i) {
        int c = tid + i * 256;
        dst[c] = (v[i] - m) * rs * g[c] + be[c];
    }
}

// ----------------------- k softmax over N=77 per (b, d), in place
__global__ __launch_bounds__(256) void ksm_k(float* __restrict__ k) {
    int gid = blockIdx.x * 256 + threadIdx.x;
    int b = gid >> 9, d = gid & 511;
    float* p = k + (size_t)b * 77 * 512 + d;
    float mx = -3.4e38f;
    for (int n = 0; n < 77; ++n) mx = fmaxf(mx, p[(size_t)n * 512]);
    float s = 0.f;
    for (int n = 0; n < 77; ++n) s += expf(p[(size_t)n * 512] - mx);
    float inv = 1.f / s;
    for (int n = 0; n < 77; ++n)
        p[(size_t)n * 512] = expf(p[(size_t)n * 512] - mx) * inv;
}

// ------------------- attn[b,h,d,e] = sum_n k[b,n,h*64+d] * v[b,n,h*64+e]
__global__ __launch_bounds__(256) void attn_k(const float* __restrict__ k,
        const float* __restrict__ v, float* __restrict__ attn) {
    constexpr int NS = 68;
    __shared__ __align__(16) float ks[77 * NS];
    __shared__ __align__(16) float vs[77 * NS];
    const int tid = threadIdx.x;
    const int b = blockIdx.x >> 3, h = blockIdx.x & 7;
    for (int idx = tid; idx < 77 * 16; idx += 256) {
        int n = idx >> 4, dq = (idx & 15) * 4;
        *(float4*)&ks[n * NS + dq] =
            *(const float4*)&k[((size_t)b * 77 + n) * 512 + h * 64 + dq];
        *(float4*)&vs[n * NS + dq] =
            *(const float4*)&v[((size_t)b * 77 + n) * 512 + h * 64 + dq];
    }
    __syncthreads();
    const int e = tid & 63, dq = tid >> 6;
    float acc[16];
#pragma unroll
    for (int u = 0; u < 16; ++u) acc[u] = 0.f;
    for (int n = 0; n < 77; ++n) {
        float vv = vs[n * NS + e];
#pragma unroll
        for (int u4 = 0; u4 < 4; ++u4) {
            float4 kk = *(const float4*)&ks[n * NS + dq * 16 + u4 * 4];
            acc[u4 * 4 + 0] = fmaf(kk.x, vv, acc[u4 * 4 + 0]);
            acc[u4 * 4 + 1] = fmaf(kk.y, vv, acc[u4 * 4 + 1]);
            acc[u4 * 4 + 2] = fmaf(kk.z, vv, acc[u4 * 4 + 2]);
            acc[u4 * 4 + 3] = fmaf(kk.w, vv, acc[u4 * 4 + 3]);
        }
    }
#pragma unroll
    for (int u = 0; u < 16; ++u)
        attn[(((size_t)b * 8 + h) * 64 + dq * 16 + u) * 64 + e] = acc[u];
}

// ---- out[cidx[b], h*64+e, t] += sum_d q[b, h*64+d, t] * attn[b,h,d,e]
__global__ __launch_bounds__(256) void yattn2_k(const float* __restrict__ q,
        const float* __restrict__ attn, const int* __restrict__ cidx,
        float* __restrict__ out) {
    __shared__ float qs[64 * 65];     // qs[d][t]
    __shared__ __align__(16) float as_[64 * 68];
    const int tid = threadIdx.x;
    const int t0 = blockIdx.x * 64, h = blockIdx.y, b = blockIdx.z;
    const int ib = cidx[b];
    for (int idx = tid; idx < 64 * 64; idx += 256) {
        int r = idx >> 6, cpos = idx & 63;
        qs[r * 65 + cpos] = q[((size_t)b * 512 + h * 64 + r) * 512 + t0 + cpos];
        as_[r * 68 + cpos] = attn[(((size_t)b * 8 + h) * 64 + r) * 64 + cpos];
    }
    __syncthreads();
    const int tl = tid & 63, eq = tid >> 6;
    float acc[16];
#pragma unroll
    for (int u = 0; u < 16; ++u) acc[u] = 0.f;
#pragma unroll 8
    for (int d = 0; d < 64; ++d) {
        float qv = qs[d * 65 + tl];
#pragma unroll
        for (int u4 = 0; u4 < 4; ++u4) {
            float4 aa = *(const float4*)&as_[d * 68 + eq * 16 + u4 * 4];
            acc[u4 * 4 + 0] = fmaf(qv, aa.x, acc[u4 * 4 + 0]);
            acc[u4 * 4 + 1] = fmaf(qv, aa.y, acc[u4 * 4 + 1]);
            acc[u4 * 4 + 2] = fmaf(qv, aa.z, acc[u4 * 4 + 2]);
            acc[u4 * 4 + 3] = fmaf(qv, aa.w, acc[u4 * 4 + 3]);
        }
    }
#pragma unroll
    for (int u = 0; u < 16; ++u)
        atomicAdd(&out[((size_t)ib * 512 + h * 64 + eq * 16 + u) * 512 + t0 + tl],
                  acc[u]);
}

extern "C" void kernel_launch(void* const* d_in, const int* in_sizes, int n_in,
                              void* d_out, int out_size, void* d_ws, size_t ws_size,
                              hipStream_t stream) {
    (void)in_sizes; (void)n_in; (void)out_size; (void)ws_size;
    const float* x       = (const float*)d_in[0];
    const float* t       = (const float*)d_in[1];
    const float* cond    = (const float*)d_in[2];
    const float* conv0_w = (const float*)d_in[3];
    const float* conv0_b = (const float*)d_in[4];
    const float* gn0_g   = (const float*)d_in[5];
    const float* gn0_b   = (const float*)d_in[6];
    const float* tm_w    = (const float*)d_in[7];
    const float* tm_b    = (const float*)d_in[8];
    const float* conv1_w = (const float*)d_in[9];
    const float* conv1_b = (const float*)d_in[10];
    const float* gn1_g   = (const float*)d_in[11];
    const float* gn1_b   = (const float*)d_in[12];
    const float* res_w   = (const float*)d_in[13];
    const float* res_b   = (const float*)d_in[14];
    const float* ln_x_g  = (const float*)d_in[15];
    const float* ln_x_b  = (const float*)d_in[16];
    const float* ln_c_g  = (const float*)d_in[17];
    const float* ln_c_b  = (const float*)d_in[18];
    const float* q_w     = (const float*)d_in[19];
    const float* q_b     = (const float*)d_in[20];
    const float* k_w     = (const float*)d_in[21];
    const float* k_b     = (const float*)d_in[22];
    const float* v_w     = (const float*)d_in[23];
    const float* v_b     = (const float*)d_in[24];
    const int*   cidx    = (const int*)d_in[25];
    float* out = (float*)d_out;

    float* wsf = (float*)d_ws;
    // phase-overlaid layout (float offsets); high-water 123.1 MB < 134.6 MB (r1-proven)
    unsigned short* xb  = (unsigned short*)(wsf + 0);          // 8.4M ush
    unsigned short* h0  = (unsigned short*)(wsf + 4194304);    // 16.8M ush
    unsigned short* h1  = (unsigned short*)(wsf + 12582912);   // 16.8M ush
    unsigned short* xln = (unsigned short*)(wsf + 0);          // after conv1: xb/h0 dead
    float* qb  = wsf + 12582912;                               // after res conv: h1 dead
    float* cn  = wsf + 0;                                      // after q proj: xln dead
    float* kb  = wsf + 3784704;
    float* vb  = wsf + 6307840;
    float* ab  = wsf + 8830976;                                // ends 10.93M < 12.58M
    float* ssb = wsf + 29360128;
    float* mt  = wsf + 29425664;
    unsigned short* wp0 = (unsigned short*)(wsf + 29458432);   // 5*512*256
    unsigned short* wp1 = (unsigned short*)(wsf + 29786112);   // 5*512*512
    unsigned short* wpr = (unsigned short*)(wsf + 30441472);   // 512*256
    unsigned short* wpq = (unsigned short*)(wsf + 30507008);   // 512*512

    // 0) pack weights to bf16 [kk][co][ci]; convert x to bf16
    pack_w<<<dim3((512*256*5)/256), dim3(256), 0, stream>>>(conv0_w, wp0, 256, 5, 512*256*5);
    pack_w<<<dim3((512*512*5)/256), dim3(256), 0, stream>>>(conv1_w, wp1, 512, 5, 512*512*5);
    pack_w<<<dim3((512*256)/256),   dim3(256), 0, stream>>>(res_w,  wpr, 256, 1, 512*256);
    pack_w<<<dim3((512*512)/256),   dim3(256), 0, stream>>>(q_w,    wpq, 512, 1, 512*512);
    cvt_bf16<<<dim3(8192), dim3(256), 0, stream>>>(x, xb, 2097152);
    // 1) ss = mish(t) @ tm_w^T + tm_b
    mish_k<<<dim3(128), dim3(256), 0, stream>>>(t, mt, 32768);
    gemm_nt<512><<<dim3(1, 16), dim3(256), 0, stream>>>(mt, tm_w, tm_b, ssb, 64, 1024);
    // 2) conv0 (MFMA) -> h0 bf16; GN + FiLM + mish in place
    conv_mfma<256, 5, true, false><<<dim3(2, 8, 64), dim3(256), 0, stream>>>(
        xb, wp0, conv0_b, (const unsigned short*)nullptr, h0);
    gn_bf<true><<<dim3(8, 64), dim3(256), 0, stream>>>(h0, gn0_g, gn0_b, ssb);
    // 3) conv1 (MFMA) -> h1 bf16; GN + mish in place
    conv_mfma<512, 5, true, false><<<dim3(2, 8, 64), dim3(256), 0, stream>>>(
        h0, wp1, conv1_b, (const unsigned short*)nullptr, h1);
    gn_bf<false><<<dim3(8, 64), dim3(256), 0, stream>>>(h1, gn1_g, gn1_b,
                                                        (const float*)nullptr);
    // 4) out = res_conv(x) + h1
    conv_mfma<256, 1, false, true><<<dim3(2, 8, 64), dim3(256), 0, stream>>>(
        xb, wpr, res_b, h1, out);
    // 5) xln = LN_channels(out[cidx]) bf16, layout [b][c][t]
    lnx_k<<<dim3(8, 64), dim3(256), 0, stream>>>(out, ln_x_g, ln_x_b, cidx, xln);
    // 6) q = q_w @ xln (MFMA, KS=1) -> q[b][d][t] fp32; softmax over Dh
    conv_mfma<512, 1, false, false><<<dim3(2, 8, 64), dim3(256), 0, stream>>>(
        xln, wpq, q_b, (const unsigned short*)nullptr, qb);
    qsm2_k<<<dim3(1024), dim3(256), 0, stream>>>(qb);
    // 7) cn = LN(cond[cidx]); k,v projections; k softmax over N
    lnc_k<<<dim3(4928), dim3(256), 0, stream>>>(cond, ln_c_g, ln_c_b, cidx, cn);
    gemm_nt<768><<<dim3(77, 8), dim3(256), 0, stream>>>(cn, k_w, k_b, kb, 4928, 512);
    gemm_nt<768><<<dim3(77, 8), dim3(256), 0, stream>>>(cn, v_w, v_b, vb, 4928, 512);
    ksm_k<<<dim3(128), dim3(256), 0, stream>>>(kb);
    // 8) attn = k^T v per (b,h); y = q @ attn scattered into out
    attn_k<<<dim3(512), dim3(256), 0, stream>>>(kb, vb, ab);
    yattn2_k<<<dim3(8, 8, 64), dim3(256), 0, stream>>>(qb, ab, cidx, out);
}

// Round 3
// 837.616 us; speedup vs baseline: 4.1841x; 1.3021x over previous
//
#include <hip/hip_runtime.h>
#include <math.h>

#define EPS 1e-5f

typedef __attribute__((ext_vector_type(8))) short short8;
typedef __attribute__((ext_vector_type(4))) float floatx4;

typedef __attribute__((address_space(1))) const void* gas1_t;
typedef __attribute__((address_space(3))) void* las3_t;

__device__ __forceinline__ void glls16(const void* g, void* l) {
    __builtin_amdgcn_global_load_lds((gas1_t)g, (las3_t)l, 16, 0, 0);
}

__device__ __forceinline__ float mishf(float x) {
    float sp = fmaxf(x, 0.0f) + log1pf(expf(-fabsf(x)));
    return x * tanhf(sp);
}
__device__ __forceinline__ unsigned short f2bf(float f) {
    unsigned int u = __float_as_uint(f);
    unsigned int r = (u + 0x7fffu + ((u >> 16) & 1u)) >> 16;
    return (unsigned short)r;
}
__device__ __forceinline__ float bf2f(unsigned short s) {
    return __uint_as_float(((unsigned int)s) << 16);
}
__device__ __forceinline__ unsigned int pk2(unsigned short a, unsigned short b) {
    return (unsigned int)a | ((unsigned int)b << 16);
}

// ---------------------------------------------------------------- mish(t)
__global__ __launch_bounds__(256) void mish_k(const float* __restrict__ t,
                                              float* __restrict__ mt, int n) {
    int i = blockIdx.x * 256 + threadIdx.x;
    if (i < n) mt[i] = mishf(t[i]);
}

// ---------------- weight pack fp32->bf16: wp[(kk*512+co)*CI+ci] = w[co][ci][kk]
__global__ __launch_bounds__(256) void pack_w(const float* __restrict__ w,
        unsigned short* __restrict__ wp, int CI, int KS, int n) {
    int o = blockIdx.x * 256 + threadIdx.x;
    if (o >= n) return;
    int ci = o % CI;
    int co = (o / CI) & 511;
    int kk = o / (CI * 512);
    wp[o] = f2bf(w[((size_t)co * CI + ci) * KS + kk]);
}

// ------------------------------------------------------- fp32 -> bf16 copy
__global__ __launch_bounds__(256) void cvt_bf16(const float* __restrict__ src,
        unsigned short* __restrict__ dst, int n4) {
    int i = blockIdx.x * 256 + threadIdx.x;
    if (i >= n4) return;
    float4 f = *(const float4*)&src[(size_t)i * 4];
    *(uint2*)&dst[(size_t)i * 4] =
        make_uint2(pk2(f2bf(f.x), f2bf(f.y)), pk2(f2bf(f.z), f2bf(f.w)));
}

// ------------- x [b][ci][l] fp32 -> xT [b][l][ci] bf16  (CI=256)
__global__ __launch_bounds__(256) void xpose_cvt(const float* __restrict__ x,
        unsigned short* __restrict__ xT) {
    __shared__ float tile[64][68];
    const int tid = threadIdx.x;
    const int l0 = blockIdx.x * 64, c0 = blockIdx.y * 64, b = blockIdx.z;
    for (int idx = tid; idx < 64 * 16; idx += 256) {
        int cr = idx >> 4, lc = (idx & 15) * 4;
        float4 f = *(const float4*)&x[((size_t)b * 256 + c0 + cr) * 512 + l0 + lc];
        tile[cr][lc] = f.x; tile[cr][lc + 1] = f.y;
        tile[cr][lc + 2] = f.z; tile[cr][lc + 3] = f.w;
    }
    __syncthreads();
    for (int idx = tid; idx < 64 * 16; idx += 256) {
        int lr = idx >> 4, cc = (idx & 15) * 4;
        *(uint2*)&xT[((size_t)b * 512 + l0 + lr) * 256 + c0 + cc] =
            make_uint2(pk2(f2bf(tile[cc][lr]), f2bf(tile[cc + 1][lr])),
                       pk2(f2bf(tile[cc + 2][lr]), f2bf(tile[cc + 3][lr])));
    }
}

// ------------------------------------------------ generic NT GEMM + bias (fp32, ss only)
template<int KD>
__global__ __launch_bounds__(256) void gemm_nt(const float* __restrict__ A,
        const float* __restrict__ W, const float* __restrict__ bias,
        float* __restrict__ C, int M, int N) {
    constexpr int ST = 20;
    __shared__ __align__(16) float As[64 * ST];
    __shared__ __align__(16) float Ws[64 * ST];
    const int tid = threadIdx.x;
    const int r0 = blockIdx.x * 64, c0 = blockIdx.y * 64;
    const int tx = tid & 15, ty = tid >> 4;
    const int lrow = tid >> 2, lk = (tid & 3) * 4;
    float acc[4][4];
#pragma unroll
    for (int i = 0; i < 4; ++i)
#pragma unroll
        for (int j = 0; j < 4; ++j) acc[i][j] = 0.f;
    for (int k0 = 0; k0 < KD; k0 += 16) {
        __syncthreads();
        *(float4*)&As[lrow * ST + lk] =
            *(const float4*)&A[(size_t)(r0 + lrow) * KD + k0 + lk];
        *(float4*)&Ws[lrow * ST + lk] =
            *(const float4*)&W[(size_t)(c0 + lrow) * KD + k0 + lk];
        __syncthreads();
#pragma unroll
        for (int kk = 0; kk < 16; kk += 4) {
            float4 av[4], wv[4];
#pragma unroll
            for (int i = 0; i < 4; ++i)
                av[i] = *(const float4*)&As[(ty + 16 * i) * ST + kk];
#pragma unroll
            for (int j = 0; j < 4; ++j)
                wv[j] = *(const float4*)&Ws[(tx + 16 * j) * ST + kk];
#pragma unroll
            for (int i = 0; i < 4; ++i)
#pragma unroll
                for (int j = 0; j < 4; ++j) {
                    acc[i][j] = fmaf(av[i].x, wv[j].x, acc[i][j]);
                    acc[i][j] = fmaf(av[i].y, wv[j].y, acc[i][j]);
                    acc[i][j] = fmaf(av[i].z, wv[j].z, acc[i][j]);
                    acc[i][j] = fmaf(av[i].w, wv[j].w, acc[i][j]);
                }
        }
    }
#pragma unroll
    for (int j = 0; j < 4; ++j) {
        int c = c0 + tx + 16 * j;
        float bv = bias[c];
#pragma unroll
        for (int i = 0; i < 4; ++i)
            C[(size_t)(r0 + ty + 16 * i) * N + c] = acc[i][j] + bv;
    }
}

// =================== MFMA conv (KS=5) with fused GN(+FiLM)+mish epilogue ===
// xb: [64][512][CI] bf16 ; wp: [5][512][CI] bf16 ; outT: [64][512][512] bf16
// block = 64 co (one GN group) x 256 l ; wave = 64co x 64l ; K chunks of 32 ci.
template<int CI, bool FILM>
__global__ __launch_bounds__(256) void conv5_mfma(
        const unsigned short* __restrict__ xb,
        const unsigned short* __restrict__ wp,
        const float* __restrict__ bias,
        const float* __restrict__ gam, const float* __restrict__ bet,
        const float* __restrict__ ss,
        unsigned short* __restrict__ outT) {
    __shared__ __align__(16) unsigned short xs[260 * 32];
    __shared__ __align__(16) unsigned short wsm[5 * 64 * 32];
    __shared__ float sgam[64], sbet[64], sbias[64], sscale[64], sshift[64];

    const int tid = threadIdx.x;
    const int l0 = blockIdx.x * 256;
    const int co0 = blockIdx.y * 64;
    const int b = blockIdx.z;
    const int lane = tid & 63;
    const int wv = tid >> 6;
    const int lq = lane & 15, qd = lane >> 4;
    const int wn = wv * 64;

    if (tid < 64) {
        int co = co0 + tid;
        sbias[tid] = bias[co];
        sgam[tid] = gam[co];
        sbet[tid] = bet[co];
        if (FILM) {
            sscale[tid] = ss[(size_t)b * 1024 + co];
            sshift[tid] = ss[(size_t)b * 1024 + 512 + co];
        }
    }

    floatx4 acc[4][4];
#pragma unroll
    for (int i = 0; i < 4; ++i)
#pragma unroll
        for (int j = 0; j < 4; ++j) acc[i][j] = (floatx4){0.f, 0.f, 0.f, 0.f};

    for (int ci0 = 0; ci0 < CI; ci0 += 32) {
        __syncthreads();
        // halo rows (LDS rows 0,1,258,259) via scalar ds_write
        if (tid < 128) {
            int rh = tid >> 5;
            int lr = (rh < 2) ? rh : (256 + rh);
            int ci_l = tid & 31;
            int gl = l0 - 2 + lr;
            unsigned short v = 0;
            if (gl >= 0 && gl < 512)
                v = xb[((size_t)b * 512 + gl) * CI + ci0 + ci_l];
            int pos = (ci_l >> 3) ^ ((lr >> 1) & 3);
            xs[lr * 32 + pos * 8 + (ci_l & 7)] = v;
        }
        // interior rows 2..257: global_load_lds dwordx4, 4 issues/wave
        {
            const unsigned short* gb = &xb[((size_t)b * 512 + l0) * CI + ci0];
#pragma unroll
            for (int it = 0; it < 4; ++it) {
                int task = it * 256 + wv * 64 + lane;
                int ri = task >> 2, pos = task & 3;
                int seg = pos ^ (((ri + 2) >> 1) & 3);
                glls16(gb + (size_t)ri * CI + seg * 8,
                       (void*)(xs + 64 + (it * 256 + wv * 64) * 8));
            }
        }
        // weights: 5 issues/wave  -> wsm[kk][co][seg]
        {
#pragma unroll
            for (int it = 0; it < 5; ++it) {
                int task = it * 256 + wv * 64 + lane;
                int kk = task >> 8;
                int r = task & 255;
                int co_l = r >> 2, pos = r & 3;
                int seg = pos ^ ((co_l >> 1) & 3);
                glls16(&wp[((size_t)(kk * 512 + co0 + co_l)) * CI + ci0 + seg * 8],
                       (void*)(wsm + (it * 256 + wv * 64) * 8));
            }
        }
        __syncthreads();
#pragma unroll
        for (int kk = 0; kk < 5; ++kk) {
            short8 bvf[4];
#pragma unroll
            for (int j = 0; j < 4; ++j) {
                int row = wn + j * 16 + lq + kk;
                int pos = qd ^ ((row >> 1) & 3);
                bvf[j] = *(const short8*)&xs[row * 32 + pos * 8];
            }
#pragma unroll
            for (int i = 0; i < 4; ++i) {
                int crow = i * 16 + lq;
                int pos = qd ^ ((crow >> 1) & 3);
                short8 av = *(const short8*)&wsm[kk * 2048 + crow * 32 + pos * 8];
#pragma unroll
                for (int j = 0; j < 4; ++j)
                    acc[i][j] = __builtin_amdgcn_mfma_f32_16x16x32_bf16(
                        av, bvf[j], acc[i][j], 0, 0, 0);
            }
        }
    }
    // ---- fused epilogue: bias, GN stats over 64 co per l, FiLM, mish, bf16
    float m_[4], rs_[4];
#pragma unroll
    for (int j = 0; j < 4; ++j) {
        float s1 = 0.f, s2 = 0.f;
#pragma unroll
        for (int i = 0; i < 4; ++i) {
            float4 bv4 = *(const float4*)&sbias[i * 16 + qd * 4];
            float ba[4] = {bv4.x, bv4.y, bv4.z, bv4.w};
#pragma unroll
            for (int r = 0; r < 4; ++r) {
                float v = acc[i][j][r] + ba[r];
                acc[i][j][r] = v;
                s1 += v; s2 += v * v;
            }
        }
        s1 += __shfl_xor(s1, 16, 64); s2 += __shfl_xor(s2, 16, 64);
        s1 += __shfl_xor(s1, 32, 64); s2 += __shfl_xor(s2, 32, 64);
        float mean = s1 * (1.f / 64.f);
        float var = s2 * (1.f / 64.f) - mean * mean;
        m_[j] = mean; rs_[j] = rsqrtf(var + EPS);
    }
#pragma unroll
    for (int j = 0; j < 4; ++j) {
        int l = l0 + wn + j * 16 + lq;
        size_t rowbase = ((size_t)b * 512 + l) * 512 + co0;
#pragma unroll
        for (int i = 0; i < 4; ++i) {
            float4 g4 = *(const float4*)&sgam[i * 16 + qd * 4];
            float4 b4 = *(const float4*)&sbet[i * 16 + qd * 4];
            float ga[4] = {g4.x, g4.y, g4.z, g4.w};
            float be[4] = {b4.x, b4.y, b4.z, b4.w};
            float sa[4] = {0, 0, 0, 0}, sh[4] = {0, 0, 0, 0};
            if (FILM) {
                float4 s4 = *(const float4*)&sscale[i * 16 + qd * 4];
                float4 h4 = *(const float4*)&sshift[i * 16 + qd * 4];
                sa[0] = s4.x; sa[1] = s4.y; sa[2] = s4.z; sa[3] = s4.w;
                sh[0] = h4.x; sh[1] = h4.y; sh[2] = h4.z; sh[3] = h4.w;
            }
            unsigned short o[4];
#pragma unroll
            for (int r = 0; r < 4; ++r) {
                float v = (acc[i][j][r] - m_[j]) * rs_[j] * ga[r] + be[r];
                if (FILM) v = v * (1.f + sa[r]) + sh[r];
                o[r] = f2bf(mishf(v));
            }
            *(uint2*)&outT[rowbase + i * 16 + qd * 4] =
                make_uint2(pk2(o[0], o[1]), pk2(o[2], o[3]));
        }
    }
}

// =================== generic MFMA GEMM (A [Mpad][KD] bf16 x W [512][KD] bf16)
// EPI 0=RES(add h1T, write d_out[b][c][t] fp32 + outTb bf16)
// EPI 1=QSM(bias+softmax over 64-n head, write bf16)
// EPI 2=KV (bias, write fp32 [m][512], guard m<Mreal)
template<int KD, int EPI>
__global__ __launch_bounds__(256) void gemm1_mfma(
        const unsigned short* __restrict__ A,
        const unsigned short* __restrict__ W,
        const float* __restrict__ bias,
        const unsigned short* __restrict__ addT,
        float* __restrict__ outF,
        unsigned short* __restrict__ outB,
        int Mreal) {
    __shared__ __align__(16) unsigned short xs[256 * 32];
    __shared__ __align__(16) unsigned short wsm[64 * 32];
    __shared__ float sbias[64];
    const int tid = threadIdx.x;
    const int m0 = blockIdx.x * 256;
    const int n0 = blockIdx.y * 64;
    const int lane = tid & 63;
    const int wv = tid >> 6;
    const int lq = lane & 15, qd = lane >> 4;
    const int wn = wv * 64;
    if (tid < 64) sbias[tid] = bias[n0 + tid];

    floatx4 acc[4][4];
#pragma unroll
    for (int i = 0; i < 4; ++i)
#pragma unroll
        for (int j = 0; j < 4; ++j) acc[i][j] = (floatx4){0.f, 0.f, 0.f, 0.f};

    for (int ci0 = 0; ci0 < KD; ci0 += 32) {
        __syncthreads();
#pragma unroll
        for (int it = 0; it < 4; ++it) {
            int task = it * 256 + wv * 64 + lane;
            int ri = task >> 2, pos = task & 3;
            int seg = pos ^ ((ri >> 1) & 3);
            glls16(&A[((size_t)(m0 + ri)) * KD + ci0 + seg * 8],
                   (void*)(xs + (it * 256 + wv * 64) * 8));
        }
        {
            int task = wv * 64 + lane;
            int co_l = task >> 2, pos = task & 3;
            int seg = pos ^ ((co_l >> 1) & 3);
            glls16(&W[((size_t)(n0 + co_l)) * KD + ci0 + seg * 8],
                   (void*)(wsm + (wv * 64) * 8));
        }
        __syncthreads();
        short8 bvf[4];
#pragma unroll
        for (int j = 0; j < 4; ++j) {
            int row = wn + j * 16 + lq;
            int pos = qd ^ ((row >> 1) & 3);
            bvf[j] = *(const short8*)&xs[row * 32 + pos * 8];
        }
#pragma unroll
        for (int i = 0; i < 4; ++i) {
            int crow = i * 16 + lq;
            int pos = qd ^ ((crow >> 1) & 3);
            short8 av = *(const short8*)&wsm[crow * 32 + pos * 8];
#pragma unroll
            for (int j = 0; j < 4; ++j)
                acc[i][j] = __builtin_amdgcn_mfma_f32_16x16x32_bf16(
                    av, bvf[j], acc[i][j], 0, 0, 0);
        }
    }
    // bias add (common)
#pragma unroll
    for (int i = 0; i < 4; ++i) {
        float4 bv4 = *(const float4*)&sbias[i * 16 + qd * 4];
        float ba[4] = {bv4.x, bv4.y, bv4.z, bv4.w};
#pragma unroll
        for (int j = 0; j < 4; ++j)
#pragma unroll
            for (int r = 0; r < 4; ++r) acc[i][j][r] += ba[r];
    }
    if (EPI == 0) {  // RES
#pragma unroll
        for (int j = 0; j < 4; ++j) {
            int m = m0 + wn + j * 16 + lq;
            int bb = m >> 9, t = m & 511;
#pragma unroll
            for (int i = 0; i < 4; ++i) {
                int n = n0 + i * 16 + qd * 4;
                uint2 hv = *(const uint2*)&addT[(size_t)m * 512 + n];
                float vr[4];
                vr[0] = acc[i][j][0] + bf2f((unsigned short)(hv.x & 0xffff));
                vr[1] = acc[i][j][1] + bf2f((unsigned short)(hv.x >> 16));
                vr[2] = acc[i][j][2] + bf2f((unsigned short)(hv.y & 0xffff));
                vr[3] = acc[i][j][3] + bf2f((unsigned short)(hv.y >> 16));
#pragma unroll
                for (int r = 0; r < 4; ++r)
                    outF[((size_t)bb * 512 + n + r) * 512 + t] = vr[r];
                *(uint2*)&outB[(size_t)m * 512 + n] =
                    make_uint2(pk2(f2bf(vr[0]), f2bf(vr[1])),
                               pk2(f2bf(vr[2]), f2bf(vr[3])));
            }
        }
    } else if (EPI == 1) {  // QSM: softmax over the 64 n of this head, per m
#pragma unroll
        for (int j = 0; j < 4; ++j) {
            float mx = -3.4e38f;
#pragma unroll
            for (int i = 0; i < 4; ++i)
#pragma unroll
                for (int r = 0; r < 4; ++r) mx = fmaxf(mx, acc[i][j][r]);
            mx = fmaxf(mx, __shfl_xor(mx, 16, 64));
            mx = fmaxf(mx, __shfl_xor(mx, 32, 64));
            float s = 0.f;
#pragma unroll
            for (int i = 0; i < 4; ++i)
#pragma unroll
                for (int r = 0; r < 4; ++r) {
                    float e = expf(acc[i][j][r] - mx);
                    acc[i][j][r] = e; s += e;
                }
            s += __shfl_xor(s, 16, 64);
            s += __shfl_xor(s, 32, 64);
            float inv = 1.f / s;
            int m = m0 + wn + j * 16 + lq;
#pragma unroll
            for (int i = 0; i < 4; ++i) {
                *(uint2*)&outB[(size_t)m * 512 + n0 + i * 16 + qd * 4] =
                    make_uint2(pk2(f2bf(acc[i][j][0] * inv), f2bf(acc[i][j][1] * inv)),
                               pk2(f2bf(acc[i][j][2] * inv), f2bf(acc[i][j][3] * inv)));
            }
        }
    } else {  // KV
#pragma unroll
        for (int j = 0; j < 4; ++j) {
            int m = m0 + wn + j * 16 + lq;
            if (m < Mreal) {
#pragma unroll
                for (int i = 0; i < 4; ++i) {
                    float4 o = {acc[i][j][0], acc[i][j][1], acc[i][j][2], acc[i][j][3]};
                    *(float4*)&outF[(size_t)m * 512 + n0 + i * 16 + qd * 4] = o;
                }
            }
        }
    }
}

// ---------- row LayerNorm of outTb[cidx[b]] (512 bf16) -> xlnT bf16
__global__ __launch_bounds__(256) void lnrow(const unsigned short* __restrict__ src,
        const float* __restrict__ g, const float* __restrict__ be,
        const int* __restrict__ cidx, unsigned short* __restrict__ dst) {
    const int tid = threadIdx.x;
    const int lane = tid & 63, wv = tid >> 6;
    const int row0 = blockIdx.x * 32 + wv * 8;
    for (int rr = 0; rr < 8; ++rr) {
        int m = row0 + rr;
        int b = m >> 9, t = m & 511;
        int ib = cidx[b];
        const unsigned short* sp = &src[((size_t)ib * 512 + t) * 512 + lane * 8];
        short8 u = *(const short8*)sp;
        float v[8];
        float s1 = 0.f, s2 = 0.f;
#pragma unroll
        for (int k = 0; k < 8; ++k) {
            v[k] = bf2f(((const unsigned short*)&u)[k]);
            s1 += v[k]; s2 += v[k] * v[k];
        }
#pragma unroll
        for (int o = 32; o > 0; o >>= 1) {
            s1 += __shfl_xor(s1, o, 64);
            s2 += __shfl_xor(s2, o, 64);
        }
        float mean = s1 * (1.f / 512.f);
        float var = s2 * (1.f / 512.f) - mean * mean;
        float rs = rsqrtf(var + EPS);
        float4 g0 = *(const float4*)&g[lane * 8];
        float4 g1 = *(const float4*)&g[lane * 8 + 4];
        float4 b0 = *(const float4*)&be[lane * 8];
        float4 b1 = *(const float4*)&be[lane * 8 + 4];
        float ga[8] = {g0.x, g0.y, g0.z, g0.w, g1.x, g1.y, g1.z, g1.w};
        float ba[8] = {b0.x, b0.y, b0.z, b0.w, b1.x, b1.y, b1.z, b1.w};
        unsigned short o8[8];
#pragma unroll
        for (int k = 0; k < 8; ++k)
            o8[k] = f2bf((v[k] - mean) * rs * ga[k] + ba[k]);
        *(uint4*)&dst[(size_t)m * 512 + lane * 8] =
            make_uint4(pk2(o8[0], o8[1]), pk2(o8[2], o8[3]),
                       pk2(o8[4], o8[5]), pk2(o8[6], o8[7]));
    }
}

// --------------------------- LayerNorm of cond rows (768) -> cnb bf16
__global__ __launch_bounds__(256) void lnc_k(const float* __restrict__ cond,
        const float* __restrict__ g, const float* __restrict__ be,
        const int* __restrict__ cidx, unsigned short* __restrict__ cn) {
    const int tid = threadIdx.x;
    const int bn = blockIdx.x;
    const int b = bn / 77, n = bn - b * 77;
    const int ib = cidx[b];
    const float* src = cond + ((size_t)ib * 77 + n) * 768;
    float v[3];
    float s = 0.f, s2 = 0.f;
#pragma unroll
    for (int i = 0; i < 3; ++i) {
        v[i] = src[tid + i * 256];
        s += v[i]; s2 += v[i] * v[i];
    }
#pragma unroll
    for (int o = 32; o > 0; o >>= 1) {
        s += __shfl_xor(s, o, 64);
        s2 += __shfl_xor(s2, o, 64);
    }
    __shared__ float r1[4], r2[4], mv[2];
    if ((tid & 63) == 0) { r1[tid >> 6] = s; r2[tid >> 6] = s2; }
    __syncthreads();
    if (tid == 0) {
        float ts = r1[0] + r1[1] + r1[2] + r1[3];
        float ts2 = r2[0] + r2[1] + r2[2] + r2[3];
        float m = ts * (1.f / 768.f);
        float var = ts2 * (1.f / 768.f) - m * m;
        mv[0] = m; mv[1] = rsqrtf(var + EPS);
    }
    __syncthreads();
    float m = mv[0], rs = mv[1];
    unsigned short* dst = cn + ((size_t)b * 77 + n) * 768;
#pragma unroll
    for (int i = 0; i < 3; ++i) {
        int c = tid + i * 256;
        dst[c] = f2bf((v[i] - m) * rs * g[c] + be[c]);
    }
}

// ----------------------- k softmax over N=77 per (b, d), in place (fp32)
__global__ __launch_bounds__(256) void ksm_k(float* __restrict__ k) {
    int gid = blockIdx.x * 256 + threadIdx.x;
    int b = gid >> 9, d = gid & 511;
    float* p = k + (size_t)b * 77 * 512 + d;
    float mx = -3.4e38f;
    for (int n = 0; n < 77; ++n) mx = fmaxf(mx, p[(size_t)n * 512]);
    float s = 0.f;
    for (int n = 0; n < 77; ++n) s += expf(p[(size_t)n * 512] - mx);
    float inv = 1.f / s;
    for (int n = 0; n < 77; ++n)
        p[(size_t)n * 512] = expf(p[(size_t)n * 512] - mx) * inv;
}

// --------- attnT[b,h,e,d] = sum_n k[b,n,h*64+d] * v[b,n,h*64+e]   (bf16 out)
__global__ __launch_bounds__(256) void attn_k(const float* __restrict__ k,
        const float* __restrict__ v, unsigned short* __restrict__ attnT) {
    constexpr int NS = 68;
    __shared__ __align__(16) float ks[77 * NS];
    __shared__ __align__(16) float vs[77 * NS];
    const int tid = threadIdx.x;
    const int b = blockIdx.x >> 3, h = blockIdx.x & 7;
    for (int idx = tid; idx < 77 * 16; idx += 256) {
        int n = idx >> 4, dq = (idx & 15) * 4;
        *(float4*)&ks[n * NS + dq] =
            *(const float4*)&k[((size_t)b * 77 + n) * 512 + h * 64 + dq];
        *(float4*)&vs[n * NS + dq] =
            *(const float4*)&v[((size_t)b * 77 + n) * 512 + h * 64 + dq];
    }
    __syncthreads();
    const int e = tid & 63, dq = tid >> 6;
    float acc[16];
#pragma unroll
    for (int u = 0; u < 16; ++u) acc[u] = 0.f;
    for (int n = 0; n < 77; ++n) {
        float vv = vs[n * NS + e];
#pragma unroll
        for (int u4 = 0; u4 < 4; ++u4) {
            float4 kk = *(const float4*)&ks[n * NS + dq * 16 + u4 * 4];
            acc[u4 * 4 + 0] = fmaf(kk.x, vv, acc[u4 * 4 + 0]);
            acc[u4 * 4 + 1] = fmaf(kk.y, vv, acc[u4 * 4 + 1]);
            acc[u4 * 4 + 2] = fmaf(kk.z, vv, acc[u4 * 4 + 2]);
            acc[u4 * 4 + 3] = fmaf(kk.w, vv, acc[u4 * 4 + 3]);
        }
    }
    // store transposed: attnT[((b*8+h)*64 + e)*64 + d], d = dq*16+u
    unsigned short ob[16];
#pragma unroll
    for (int u = 0; u < 16; ++u) ob[u] = f2bf(acc[u]);
    size_t base = (((size_t)b * 8 + h) * 64 + e) * 64 + dq * 16;
    *(uint4*)&attnT[base] = make_uint4(pk2(ob[0], ob[1]), pk2(ob[2], ob[3]),
                                       pk2(ob[4], ob[5]), pk2(ob[6], ob[7]));
    *(uint4*)&attnT[base + 8] = make_uint4(pk2(ob[8], ob[9]), pk2(ob[10], ob[11]),
                                           pk2(ob[12], ob[13]), pk2(ob[14], ob[15]));
}

// ---- out[cidx[b], h*64+e, t] += sum_d q[b,t,h*64+d] * attnT[b,h,e,d]  (MFMA)
__global__ __launch_bounds__(256) void yattn_mfma(
        const unsigned short* __restrict__ q,
        const unsigned short* __restrict__ at,
        const int* __restrict__ cidx, float* __restrict__ out) {
    const int tid = threadIdx.x;
    const int lane = tid & 63, wv = tid >> 6;
    const int lq = lane & 15, qd = lane >> 4;
    const int t0 = blockIdx.x * 256 + wv * 64;
    const int h = blockIdx.y, b = blockIdx.z;
    const int ib = cidx[b];
    floatx4 acc[4][4];
#pragma unroll
    for (int i = 0; i < 4; ++i)
#pragma unroll
        for (int j = 0; j < 4; ++j) acc[i][j] = (floatx4){0.f, 0.f, 0.f, 0.f};
#pragma unroll
    for (int ks = 0; ks < 2; ++ks) {
        short8 av[4], bv[4];
#pragma unroll
        for (int i = 0; i < 4; ++i)
            av[i] = *(const short8*)
                &q[((size_t)(b * 512 + t0 + i * 16 + lq)) * 512 + h * 64 + ks * 32 + qd * 8];
#pragma unroll
        for (int j = 0; j < 4; ++j)
            bv[j] = *(const short8*)
                &at[(((size_t)(b * 8 + h)) * 64 + j * 16 + lq) * 64 + ks * 32 + qd * 8];
#pragma unroll
        for (int i = 0; i < 4; ++i)
#pragma unroll
            for (int j = 0; j < 4; ++j)
                acc[i][j] = __builtin_amdgcn_mfma_f32_16x16x32_bf16(
                    av[i], bv[j], acc[i][j], 0, 0, 0);
    }
#pragma unroll
    for (int i = 0; i < 4; ++i)
#pragma unroll
        for (int j = 0; j < 4; ++j) {
            int e = j * 16 + lq;
#pragma unroll
            for (int r = 0; r < 4; ++r) {
                int t = t0 + i * 16 + qd * 4 + r;
                atomicAdd(&out[((size_t)ib * 512 + h * 64 + e) * 512 + t],
                          acc[i][j][r]);
            }
        }
}

extern "C" void kernel_launch(void* const* d_in, const int* in_sizes, int n_in,
                              void* d_out, int out_size, void* d_ws, size_t ws_size,
                              hipStream_t stream) {
    (void)in_sizes; (void)n_in; (void)out_size; (void)ws_size;
    const float* x       = (const float*)d_in[0];
    const float* t       = (const float*)d_in[1];
    const float* cond    = (const float*)d_in[2];
    const float* conv0_w = (const float*)d_in[3];
    const float* conv0_b = (const float*)d_in[4];
    const float* gn0_g   = (const float*)d_in[5];
    const float* gn0_b   = (const float*)d_in[6];
    const float* tm_w    = (const float*)d_in[7];
    const float* tm_b    = (const float*)d_in[8];
    const float* conv1_w = (const float*)d_in[9];
    const float* conv1_b = (const float*)d_in[10];
    const float* gn1_g   = (const float*)d_in[11];
    const float* gn1_b   = (const float*)d_in[12];
    const float* res_w   = (const float*)d_in[13];
    const float* res_b   = (const float*)d_in[14];
    const float* ln_x_g  = (const float*)d_in[15];
    const float* ln_x_b  = (const float*)d_in[16];
    const float* ln_c_g  = (const float*)d_in[17];
    const float* ln_c_b  = (const float*)d_in[18];
    const float* q_w     = (const float*)d_in[19];
    const float* q_b     = (const float*)d_in[20];
    const float* k_w     = (const float*)d_in[21];
    const float* k_b     = (const float*)d_in[22];
    const float* v_w     = (const float*)d_in[23];
    const float* v_b     = (const float*)d_in[24];
    const int*   cidx    = (const int*)d_in[25];
    float* out = (float*)d_out;

    char* WS = (char*)d_ws;
    // byte-offset overlay (high-water ~120.2 MB; 122.5 MB proven available in R1)
    unsigned short* xT    = (unsigned short*)(WS + 0);           // 16.78 MB, steps 4-8
    unsigned short* cnb   = (unsigned short*)(WS + 0);           // 7.86 MB, steps 12-14
    unsigned short* attnT = (unsigned short*)(WS + 8388608);     // 4.19 MB, 16-17
    unsigned short* h0T   = (unsigned short*)(WS + 16777216);    // 33.55 MB, 6-7
    unsigned short* xlnT  = (unsigned short*)(WS + 16777216);    // 33.55 MB, 10-11
    float*          kb    = (float*)(WS + 16777216);             // 10.09 MB, 13-16
    float*          vb    = (float*)(WS + 26869760);             // 10.09 MB, 14-16
    unsigned short* h1T   = (unsigned short*)(WS + 50331648);    // 33.55 MB, 7-8
    unsigned short* qbf   = (unsigned short*)(WS + 50331648);    // 33.55 MB, 11-17
    unsigned short* outTb = (unsigned short*)(WS + 83886080);    // 33.55 MB, 8-10
    unsigned short* wp0   = (unsigned short*)(WS + 83886080);    // 2.62 MB, 1-6
    unsigned short* wp1   = (unsigned short*)(WS + 86507520);    // 5.24 MB, 2-7
    unsigned short* wr    = (unsigned short*)(WS + 117440512);   // 0.26 MB
    unsigned short* wq    = (unsigned short*)(WS + 117702656);   // 0.52 MB
    unsigned short* wk    = (unsigned short*)(WS + 118226944);   // 0.79 MB
    unsigned short* wvv   = (unsigned short*)(WS + 119013376);   // 0.79 MB
    float*          ssb   = (float*)(WS + 119799808);            // 0.26 MB
    float*          mt    = (float*)(WS + 120061952);            // 0.13 MB

    // 0) weight packs / converts
    pack_w<<<dim3((512*256*5)/256), dim3(256), 0, stream>>>(conv0_w, wp0, 256, 5, 512*256*5);
    pack_w<<<dim3((512*512*5)/256), dim3(256), 0, stream>>>(conv1_w, wp1, 512, 5, 512*512*5);
    cvt_bf16<<<dim3(128),  dim3(256), 0, stream>>>(res_w, wr, 32768);
    cvt_bf16<<<dim3(256),  dim3(256), 0, stream>>>(q_w,   wq, 65536);
    cvt_bf16<<<dim3(384),  dim3(256), 0, stream>>>(k_w,   wk, 98304);
    cvt_bf16<<<dim3(384),  dim3(256), 0, stream>>>(v_w,   wvv, 98304);
    // x -> xT bf16 [b][l][ci]
    xpose_cvt<<<dim3(8, 4, 64), dim3(256), 0, stream>>>(x, xT);
    // 1) ss = mish(t) @ tm_w^T + tm_b
    mish_k<<<dim3(128), dim3(256), 0, stream>>>(t, mt, 32768);
    gemm_nt<512><<<dim3(1, 16), dim3(256), 0, stream>>>(mt, tm_w, tm_b, ssb, 64, 1024);
    // 2) conv0 + GN0 + FiLM + mish -> h0T
    conv5_mfma<256, true><<<dim3(2, 8, 64), dim3(256), 0, stream>>>(
        xT, wp0, conv0_b, gn0_g, gn0_b, ssb, h0T);
    // 3) conv1 + GN1 + mish -> h1T
    conv5_mfma<512, false><<<dim3(2, 8, 64), dim3(256), 0, stream>>>(
        h0T, wp1, conv1_b, gn1_g, gn1_b, (const float*)nullptr, h1T);
    // 4) res GEMM + add h1T -> d_out [b][c][t] fp32 AND outTb bf16 [m][c]
    gemm1_mfma<256, 0><<<dim3(128, 8), dim3(256), 0, stream>>>(
        xT, wr, res_b, h1T, out, outTb, 32768);
    // 5) row-LN of outTb[cidx] -> xlnT bf16
    lnrow<<<dim3(1024), dim3(256), 0, stream>>>(outTb, ln_x_g, ln_x_b, cidx, xlnT);
    // 6) q GEMM + per-head softmax -> qbf bf16
    gemm1_mfma<512, 1><<<dim3(128, 8), dim3(256), 0, stream>>>(
        xlnT, wq, q_b, (const unsigned short*)nullptr, (float*)nullptr, qbf, 32768);
    // 7) cond LN -> cnb bf16; k/v GEMMs fp32; k softmax over n
    lnc_k<<<dim3(4928), dim3(256), 0, stream>>>(cond, ln_c_g, ln_c_b, cidx, cnb);
    gemm1_mfma<768, 2><<<dim3(20, 8), dim3(256), 0, stream>>>(
        cnb, wk, k_b, (const unsigned short*)nullptr, kb, (unsigned short*)nullptr, 4928);
    gemm1_mfma<768, 2><<<dim3(20, 8), dim3(256), 0, stream>>>(
        cnb, wvv, v_b, (const unsigned short*)nullptr, vb, (unsigned short*)nullptr, 4928);
    ksm_k<<<dim3(128), dim3(256), 0, stream>>>(kb);
    // 8) attn = k^T v (bf16, e-major); y = q @ attn scattered into out
    attn_k<<<dim3(512), dim3(256), 0, stream>>>(kb, vb, attnT);
    yattn_mfma<<<dim3(2, 8, 64), dim3(256), 0, stream>>>(qbf, attnT, cidx, out);
}

// Round 4
// 651.468 us; speedup vs baseline: 5.3797x; 1.2857x over previous
//
#include <hip/hip_runtime.h>
#include <math.h>

#define EPS 1e-5f

typedef __attribute__((ext_vector_type(8))) short short8;
typedef __attribute__((ext_vector_type(4))) float floatx4;

typedef __attribute__((address_space(1))) const void* gas1_t;
typedef __attribute__((address_space(3))) void* las3_t;

__device__ __forceinline__ void glls16(const void* g, void* l) {
    __builtin_amdgcn_global_load_lds((gas1_t)g, (las3_t)l, 16, 0, 0);
}

__device__ __forceinline__ float mishf(float x) {
    float sp = fmaxf(x, 0.0f) + log1pf(expf(-fabsf(x)));
    return x * tanhf(sp);
}
__device__ __forceinline__ unsigned short f2bf(float f) {
    unsigned int u = __float_as_uint(f);
    unsigned int r = (u + 0x7fffu + ((u >> 16) & 1u)) >> 16;
    return (unsigned short)r;
}
__device__ __forceinline__ float bf2f(unsigned short s) {
    return __uint_as_float(((unsigned int)s) << 16);
}
__device__ __forceinline__ unsigned int pk2(unsigned short a, unsigned short b) {
    return (unsigned int)a | ((unsigned int)b << 16);
}

// ---------------------------------------------------------------- mish(t)
__global__ __launch_bounds__(256) void mish_k(const float* __restrict__ t,
                                              float* __restrict__ mt, int n) {
    int i = blockIdx.x * 256 + threadIdx.x;
    if (i < n) mt[i] = mishf(t[i]);
}

// ---------------- weight pack fp32->bf16: wp[(kk*512+co)*CI+ci] = w[co][ci][kk]
__global__ __launch_bounds__(256) void pack_w(const float* __restrict__ w,
        unsigned short* __restrict__ wp, int CI, int KS, int n) {
    int o = blockIdx.x * 256 + threadIdx.x;
    if (o >= n) return;
    int ci = o % CI;
    int co = (o / CI) & 511;
    int kk = o / (CI * 512);
    wp[o] = f2bf(w[((size_t)co * CI + ci) * KS + kk]);
}

// ------------------------------------------------------- fp32 -> bf16 copy
__global__ __launch_bounds__(256) void cvt_bf16(const float* __restrict__ src,
        unsigned short* __restrict__ dst, int n4) {
    int i = blockIdx.x * 256 + threadIdx.x;
    if (i >= n4) return;
    float4 f = *(const float4*)&src[(size_t)i * 4];
    *(uint2*)&dst[(size_t)i * 4] =
        make_uint2(pk2(f2bf(f.x), f2bf(f.y)), pk2(f2bf(f.z), f2bf(f.w)));
}

// ------------- x [b][ci][l] fp32 -> xT [b][l][ci] bf16  (CI=256)
__global__ __launch_bounds__(256) void xpose_cvt(const float* __restrict__ x,
        unsigned short* __restrict__ xT) {
    __shared__ float tile[64][68];
    const int tid = threadIdx.x;
    const int l0 = blockIdx.x * 64, c0 = blockIdx.y * 64, b = blockIdx.z;
    for (int idx = tid; idx < 64 * 16; idx += 256) {
        int cr = idx >> 4, lc = (idx & 15) * 4;
        float4 f = *(const float4*)&x[((size_t)b * 256 + c0 + cr) * 512 + l0 + lc];
        tile[cr][lc] = f.x; tile[cr][lc + 1] = f.y;
        tile[cr][lc + 2] = f.z; tile[cr][lc + 3] = f.w;
    }
    __syncthreads();
    for (int idx = tid; idx < 64 * 16; idx += 256) {
        int lr = idx >> 4, cc = (idx & 15) * 4;
        *(uint2*)&xT[((size_t)b * 512 + l0 + lr) * 256 + c0 + cc] =
            make_uint2(pk2(f2bf(tile[cc][lr]), f2bf(tile[cc + 1][lr])),
                       pk2(f2bf(tile[cc + 2][lr]), f2bf(tile[cc + 3][lr])));
    }
}

// ------------------------------------------------ generic NT GEMM + bias (fp32, ss only)
template<int KD>
__global__ __launch_bounds__(256) void gemm_nt(const float* __restrict__ A,
        const float* __restrict__ W, const float* __restrict__ bias,
        float* __restrict__ C, int M, int N) {
    constexpr int ST = 20;
    __shared__ __align__(16) float As[64 * ST];
    __shared__ __align__(16) float Ws[64 * ST];
    const int tid = threadIdx.x;
    const int r0 = blockIdx.x * 64, c0 = blockIdx.y * 64;
    const int tx = tid & 15, ty = tid >> 4;
    const int lrow = tid >> 2, lk = (tid & 3) * 4;
    float acc[4][4];
#pragma unroll
    for (int i = 0; i < 4; ++i)
#pragma unroll
        for (int j = 0; j < 4; ++j) acc[i][j] = 0.f;
    for (int k0 = 0; k0 < KD; k0 += 16) {
        __syncthreads();
        *(float4*)&As[lrow * ST + lk] =
            *(const float4*)&A[(size_t)(r0 + lrow) * KD + k0 + lk];
        *(float4*)&Ws[lrow * ST + lk] =
            *(const float4*)&W[(size_t)(c0 + lrow) * KD + k0 + lk];
        __syncthreads();
#pragma unroll
        for (int kk = 0; kk < 16; kk += 4) {
            float4 av[4], wv[4];
#pragma unroll
            for (int i = 0; i < 4; ++i)
                av[i] = *(const float4*)&As[(ty + 16 * i) * ST + kk];
#pragma unroll
            for (int j = 0; j < 4; ++j)
                wv[j] = *(const float4*)&Ws[(tx + 16 * j) * ST + kk];
#pragma unroll
            for (int i = 0; i < 4; ++i)
#pragma unroll
                for (int j = 0; j < 4; ++j) {
                    acc[i][j] = fmaf(av[i].x, wv[j].x, acc[i][j]);
                    acc[i][j] = fmaf(av[i].y, wv[j].y, acc[i][j]);
                    acc[i][j] = fmaf(av[i].z, wv[j].z, acc[i][j]);
                    acc[i][j] = fmaf(av[i].w, wv[j].w, acc[i][j]);
                }
        }
    }
#pragma unroll
    for (int j = 0; j < 4; ++j) {
        int c = c0 + tx + 16 * j;
        float bv = bias[c];
#pragma unroll
        for (int i = 0; i < 4; ++i)
            C[(size_t)(r0 + ty + 16 * i) * N + c] = acc[i][j] + bv;
    }
}

// =================== MFMA conv (KS=5) with fused GN(+FiLM)+mish epilogue ===
// xb: [64][512][CI] bf16 ; wp: [5][512][CI] bf16 ; outT: [64][512][512] bf16
template<int CI, bool FILM>
__global__ __launch_bounds__(256) void conv5_mfma(
        const unsigned short* __restrict__ xb,
        const unsigned short* __restrict__ wp,
        const float* __restrict__ bias,
        const float* __restrict__ gam, const float* __restrict__ bet,
        const float* __restrict__ ss,
        unsigned short* __restrict__ outT) {
    __shared__ __align__(16) unsigned short xs[260 * 32];
    __shared__ __align__(16) unsigned short wsm[5 * 64 * 32];
    __shared__ float sgam[64], sbet[64], sbias[64], sscale[64], sshift[64];

    const int tid = threadIdx.x;
    const int l0 = blockIdx.x * 256;
    const int co0 = blockIdx.y * 64;
    const int b = blockIdx.z;
    const int lane = tid & 63;
    const int wv = tid >> 6;
    const int lq = lane & 15, qd = lane >> 4;
    const int wn = wv * 64;

    if (tid < 64) {
        int co = co0 + tid;
        sbias[tid] = bias[co];
        sgam[tid] = gam[co];
        sbet[tid] = bet[co];
        if (FILM) {
            sscale[tid] = ss[(size_t)b * 1024 + co];
            sshift[tid] = ss[(size_t)b * 1024 + 512 + co];
        }
    }

    floatx4 acc[4][4];
#pragma unroll
    for (int i = 0; i < 4; ++i)
#pragma unroll
        for (int j = 0; j < 4; ++j) acc[i][j] = (floatx4){0.f, 0.f, 0.f, 0.f};

    for (int ci0 = 0; ci0 < CI; ci0 += 32) {
        __syncthreads();
        if (tid < 128) {
            int rh = tid >> 5;
            int lr = (rh < 2) ? rh : (256 + rh);
            int ci_l = tid & 31;
            int gl = l0 - 2 + lr;
            unsigned short v = 0;
            if (gl >= 0 && gl < 512)
                v = xb[((size_t)b * 512 + gl) * CI + ci0 + ci_l];
            int pos = (ci_l >> 3) ^ ((lr >> 1) & 3);
            xs[lr * 32 + pos * 8 + (ci_l & 7)] = v;
        }
        {
            const unsigned short* gb = &xb[((size_t)b * 512 + l0) * CI + ci0];
#pragma unroll
            for (int it = 0; it < 4; ++it) {
                int task = it * 256 + wv * 64 + lane;
                int ri = task >> 2, pos = task & 3;
                int seg = pos ^ (((ri + 2) >> 1) & 3);
                glls16(gb + (size_t)ri * CI + seg * 8,
                       (void*)(xs + 64 + (it * 256 + wv * 64) * 8));
            }
        }
        {
#pragma unroll
            for (int it = 0; it < 5; ++it) {
                int task = it * 256 + wv * 64 + lane;
                int kk = task >> 8;
                int r = task & 255;
                int co_l = r >> 2, pos = r & 3;
                int seg = pos ^ ((co_l >> 1) & 3);
                glls16(&wp[((size_t)(kk * 512 + co0 + co_l)) * CI + ci0 + seg * 8],
                       (void*)(wsm + (it * 256 + wv * 64) * 8));
            }
        }
        __syncthreads();
#pragma unroll
        for (int kk = 0; kk < 5; ++kk) {
            short8 bvf[4];
#pragma unroll
            for (int j = 0; j < 4; ++j) {
                int row = wn + j * 16 + lq + kk;
                int pos = qd ^ ((row >> 1) & 3);
                bvf[j] = *(const short8*)&xs[row * 32 + pos * 8];
            }
#pragma unroll
            for (int i = 0; i < 4; ++i) {
                int crow = i * 16 + lq;
                int pos = qd ^ ((crow >> 1) & 3);
                short8 av = *(const short8*)&wsm[kk * 2048 + crow * 32 + pos * 8];
#pragma unroll
                for (int j = 0; j < 4; ++j)
                    acc[i][j] = __builtin_amdgcn_mfma_f32_16x16x32_bf16(
                        av, bvf[j], acc[i][j], 0, 0, 0);
            }
        }
    }
    float m_[4], rs_[4];
#pragma unroll
    for (int j = 0; j < 4; ++j) {
        float s1 = 0.f, s2 = 0.f;
#pragma unroll
        for (int i = 0; i < 4; ++i) {
            float4 bv4 = *(const float4*)&sbias[i * 16 + qd * 4];
            float ba[4] = {bv4.x, bv4.y, bv4.z, bv4.w};
#pragma unroll
            for (int r = 0; r < 4; ++r) {
                float v = acc[i][j][r] + ba[r];
                acc[i][j][r] = v;
                s1 += v; s2 += v * v;
            }
        }
        s1 += __shfl_xor(s1, 16, 64); s2 += __shfl_xor(s2, 16, 64);
        s1 += __shfl_xor(s1, 32, 64); s2 += __shfl_xor(s2, 32, 64);
        float mean = s1 * (1.f / 64.f);
        float var = s2 * (1.f / 64.f) - mean * mean;
        m_[j] = mean; rs_[j] = rsqrtf(var + EPS);
    }
#pragma unroll
    for (int j = 0; j < 4; ++j) {
        int l = l0 + wn + j * 16 + lq;
        size_t rowbase = ((size_t)b * 512 + l) * 512 + co0;
#pragma unroll
        for (int i = 0; i < 4; ++i) {
            float4 g4 = *(const float4*)&sgam[i * 16 + qd * 4];
            float4 b4 = *(const float4*)&sbet[i * 16 + qd * 4];
            float ga[4] = {g4.x, g4.y, g4.z, g4.w};
            float be[4] = {b4.x, b4.y, b4.z, b4.w};
            float sa[4] = {0, 0, 0, 0}, sh[4] = {0, 0, 0, 0};
            if (FILM) {
                float4 s4 = *(const float4*)&sscale[i * 16 + qd * 4];
                float4 h4 = *(const float4*)&sshift[i * 16 + qd * 4];
                sa[0] = s4.x; sa[1] = s4.y; sa[2] = s4.z; sa[3] = s4.w;
                sh[0] = h4.x; sh[1] = h4.y; sh[2] = h4.z; sh[3] = h4.w;
            }
            unsigned short o[4];
#pragma unroll
            for (int r = 0; r < 4; ++r) {
                float v = (acc[i][j][r] - m_[j]) * rs_[j] * ga[r] + be[r];
                if (FILM) v = v * (1.f + sa[r]) + sh[r];
                o[r] = f2bf(mishf(v));
            }
            *(uint2*)&outT[rowbase + i * 16 + qd * 4] =
                make_uint2(pk2(o[0], o[1]), pk2(o[2], o[3]));
        }
    }
}

// =================== generic MFMA GEMM (A [Mpad][KD] bf16 x W [512][KD] bf16)
// EPI 0=RES(add h1T, write outTb bf16 token-major ONLY)
// EPI 1=QSM(bias+softmax over 64-n head, write bf16)
// EPI 2=KV (bias, write fp32 [m][512], guard m<Mreal)
template<int KD, int EPI>
__global__ __launch_bounds__(256) void gemm1_mfma(
        const unsigned short* __restrict__ A,
        const unsigned short* __restrict__ W,
        const float* __restrict__ bias,
        const unsigned short* __restrict__ addT,
        float* __restrict__ outF,
        unsigned short* __restrict__ outB,
        int Mreal) {
    __shared__ __align__(16) unsigned short xs[256 * 32];
    __shared__ __align__(16) unsigned short wsm[64 * 32];
    __shared__ float sbias[64];
    const int tid = threadIdx.x;
    const int m0 = blockIdx.x * 256;
    const int n0 = blockIdx.y * 64;
    const int lane = tid & 63;
    const int wv = tid >> 6;
    const int lq = lane & 15, qd = lane >> 4;
    const int wn = wv * 64;
    if (tid < 64) sbias[tid] = bias[n0 + tid];

    floatx4 acc[4][4];
#pragma unroll
    for (int i = 0; i < 4; ++i)
#pragma unroll
        for (int j = 0; j < 4; ++j) acc[i][j] = (floatx4){0.f, 0.f, 0.f, 0.f};

    for (int ci0 = 0; ci0 < KD; ci0 += 32) {
        __syncthreads();
#pragma unroll
        for (int it = 0; it < 4; ++it) {
            int task = it * 256 + wv * 64 + lane;
            int ri = task >> 2, pos = task & 3;
            int seg = pos ^ ((ri >> 1) & 3);
            glls16(&A[((size_t)(m0 + ri)) * KD + ci0 + seg * 8],
                   (void*)(xs + (it * 256 + wv * 64) * 8));
        }
        {
            int task = wv * 64 + lane;
            int co_l = task >> 2, pos = task & 3;
            int seg = pos ^ ((co_l >> 1) & 3);
            glls16(&W[((size_t)(n0 + co_l)) * KD + ci0 + seg * 8],
                   (void*)(wsm + (wv * 64) * 8));
        }
        __syncthreads();
        short8 bvf[4];
#pragma unroll
        for (int j = 0; j < 4; ++j) {
            int row = wn + j * 16 + lq;
            int pos = qd ^ ((row >> 1) & 3);
            bvf[j] = *(const short8*)&xs[row * 32 + pos * 8];
        }
#pragma unroll
        for (int i = 0; i < 4; ++i) {
            int crow = i * 16 + lq;
            int pos = qd ^ ((crow >> 1) & 3);
            short8 av = *(const short8*)&wsm[crow * 32 + pos * 8];
#pragma unroll
            for (int j = 0; j < 4; ++j)
                acc[i][j] = __builtin_amdgcn_mfma_f32_16x16x32_bf16(
                    av, bvf[j], acc[i][j], 0, 0, 0);
        }
    }
#pragma unroll
    for (int i = 0; i < 4; ++i) {
        float4 bv4 = *(const float4*)&sbias[i * 16 + qd * 4];
        float ba[4] = {bv4.x, bv4.y, bv4.z, bv4.w};
#pragma unroll
        for (int j = 0; j < 4; ++j)
#pragma unroll
            for (int r = 0; r < 4; ++r) acc[i][j][r] += ba[r];
    }
    if (EPI == 0) {  // RES: outTb[m][n] = bf16(res + h1)
#pragma unroll
        for (int j = 0; j < 4; ++j) {
            int m = m0 + wn + j * 16 + lq;
#pragma unroll
            for (int i = 0; i < 4; ++i) {
                int n = n0 + i * 16 + qd * 4;
                uint2 hv = *(const uint2*)&addT[(size_t)m * 512 + n];
                float vr[4];
                vr[0] = acc[i][j][0] + bf2f((unsigned short)(hv.x & 0xffff));
                vr[1] = acc[i][j][1] + bf2f((unsigned short)(hv.x >> 16));
                vr[2] = acc[i][j][2] + bf2f((unsigned short)(hv.y & 0xffff));
                vr[3] = acc[i][j][3] + bf2f((unsigned short)(hv.y >> 16));
                *(uint2*)&outB[(size_t)m * 512 + n] =
                    make_uint2(pk2(f2bf(vr[0]), f2bf(vr[1])),
                               pk2(f2bf(vr[2]), f2bf(vr[3])));
            }
        }
    } else if (EPI == 1) {  // QSM
#pragma unroll
        for (int j = 0; j < 4; ++j) {
            float mx = -3.4e38f;
#pragma unroll
            for (int i = 0; i < 4; ++i)
#pragma unroll
                for (int r = 0; r < 4; ++r) mx = fmaxf(mx, acc[i][j][r]);
            mx = fmaxf(mx, __shfl_xor(mx, 16, 64));
            mx = fmaxf(mx, __shfl_xor(mx, 32, 64));
            float s = 0.f;
#pragma unroll
            for (int i = 0; i < 4; ++i)
#pragma unroll
                for (int r = 0; r < 4; ++r) {
                    float e = expf(acc[i][j][r] - mx);
                    acc[i][j][r] = e; s += e;
                }
            s += __shfl_xor(s, 16, 64);
            s += __shfl_xor(s, 32, 64);
            float inv = 1.f / s;
            int m = m0 + wn + j * 16 + lq;
#pragma unroll
            for (int i = 0; i < 4; ++i) {
                *(uint2*)&outB[(size_t)m * 512 + n0 + i * 16 + qd * 4] =
                    make_uint2(pk2(f2bf(acc[i][j][0] * inv), f2bf(acc[i][j][1] * inv)),
                               pk2(f2bf(acc[i][j][2] * inv), f2bf(acc[i][j][3] * inv)));
            }
        }
    } else {  // KV
#pragma unroll
        for (int j = 0; j < 4; ++j) {
            int m = m0 + wn + j * 16 + lq;
            if (m < Mreal) {
#pragma unroll
                for (int i = 0; i < 4; ++i) {
                    float4 o = {acc[i][j][0], acc[i][j][1], acc[i][j][2], acc[i][j][3]};
                    *(float4*)&outF[(size_t)m * 512 + n0 + i * 16 + qd * 4] = o;
                }
            }
        }
    }
}

// ---------- row LayerNorm of outTb[cidx[b]] (512 bf16) -> xlnT bf16
__global__ __launch_bounds__(256) void lnrow(const unsigned short* __restrict__ src,
        const float* __restrict__ g, const float* __restrict__ be,
        const int* __restrict__ cidx, unsigned short* __restrict__ dst) {
    const int tid = threadIdx.x;
    const int lane = tid & 63, wv = tid >> 6;
    const int row0 = blockIdx.x * 32 + wv * 8;
    for (int rr = 0; rr < 8; ++rr) {
        int m = row0 + rr;
        int b = m >> 9, t = m & 511;
        int ib = cidx[b];
        const unsigned short* sp = &src[((size_t)ib * 512 + t) * 512 + lane * 8];
        short8 u = *(const short8*)sp;
        float v[8];
        float s1 = 0.f, s2 = 0.f;
#pragma unroll
        for (int k = 0; k < 8; ++k) {
            v[k] = bf2f(((const unsigned short*)&u)[k]);
            s1 += v[k]; s2 += v[k] * v[k];
        }
#pragma unroll
        for (int o = 32; o > 0; o >>= 1) {
            s1 += __shfl_xor(s1, o, 64);
            s2 += __shfl_xor(s2, o, 64);
        }
        float mean = s1 * (1.f / 512.f);
        float var = s2 * (1.f / 512.f) - mean * mean;
        float rs = rsqrtf(var + EPS);
        float4 g0 = *(const float4*)&g[lane * 8];
        float4 g1 = *(const float4*)&g[lane * 8 + 4];
        float4 b0 = *(const float4*)&be[lane * 8];
        float4 b1 = *(const float4*)&be[lane * 8 + 4];
        float ga[8] = {g0.x, g0.y, g0.z, g0.w, g1.x, g1.y, g1.z, g1.w};
        float ba[8] = {b0.x, b0.y, b0.z, b0.w, b1.x, b1.y, b1.z, b1.w};
        unsigned short o8[8];
#pragma unroll
        for (int k = 0; k < 8; ++k)
            o8[k] = f2bf((v[k] - mean) * rs * ga[k] + ba[k]);
        *(uint4*)&dst[(size_t)m * 512 + lane * 8] =
            make_uint4(pk2(o8[0], o8[1]), pk2(o8[2], o8[3]),
                       pk2(o8[4], o8[5]), pk2(o8[6], o8[7]));
    }
}

// --------------------------- LayerNorm of cond rows (768) -> cnb bf16
__global__ __launch_bounds__(256) void lnc_k(const float* __restrict__ cond,
        const float* __restrict__ g, const float* __restrict__ be,
        const int* __restrict__ cidx, unsigned short* __restrict__ cn) {
    const int tid = threadIdx.x;
    const int bn = blockIdx.x;
    const int b = bn / 77, n = bn - b * 77;
    const int ib = cidx[b];
    const float* src = cond + ((size_t)ib * 77 + n) * 768;
    float v[3];
    float s = 0.f, s2 = 0.f;
#pragma unroll
    for (int i = 0; i < 3; ++i) {
        v[i] = src[tid + i * 256];
        s += v[i]; s2 += v[i] * v[i];
    }
#pragma unroll
    for (int o = 32; o > 0; o >>= 1) {
        s += __shfl_xor(s, o, 64);
        s2 += __shfl_xor(s2, o, 64);
    }
    __shared__ float r1[4], r2[4], mv[2];
    if ((tid & 63) == 0) { r1[tid >> 6] = s; r2[tid >> 6] = s2; }
    __syncthreads();
    if (tid == 0) {
        float ts = r1[0] + r1[1] + r1[2] + r1[3];
        float ts2 = r2[0] + r2[1] + r2[2] + r2[3];
        float m = ts * (1.f / 768.f);
        float var = ts2 * (1.f / 768.f) - m * m;
        mv[0] = m; mv[1] = rsqrtf(var + EPS);
    }
    __syncthreads();
    float m = mv[0], rs = mv[1];
    unsigned short* dst = cn + ((size_t)b * 77 + n) * 768;
#pragma unroll
    for (int i = 0; i < 3; ++i) {
        int c = tid + i * 256;
        dst[c] = f2bf((v[i] - m) * rs * g[c] + be[c]);
    }
}

// ----------------------- k softmax over N=77 per (b, d), in place (fp32)
__global__ __launch_bounds__(256) void ksm_k(float* __restrict__ k) {
    int gid = blockIdx.x * 256 + threadIdx.x;
    int b = gid >> 9, d = gid & 511;
    float* p = k + (size_t)b * 77 * 512 + d;
    float mx = -3.4e38f;
    for (int n = 0; n < 77; ++n) mx = fmaxf(mx, p[(size_t)n * 512]);
    float s = 0.f;
    for (int n = 0; n < 77; ++n) s += expf(p[(size_t)n * 512] - mx);
    float inv = 1.f / s;
    for (int n = 0; n < 77; ++n)
        p[(size_t)n * 512] = expf(p[(size_t)n * 512] - mx) * inv;
}

// --------- attnT[b,h,e,d] = sum_n k[b,n,h*64+d] * v[b,n,h*64+e]   (bf16 out)
__global__ __launch_bounds__(256) void attn_k(const float* __restrict__ k,
        const float* __restrict__ v, unsigned short* __restrict__ attnT) {
    constexpr int NS = 68;
    __shared__ __align__(16) float ks[77 * NS];
    __shared__ __align__(16) float vs[77 * NS];
    const int tid = threadIdx.x;
    const int b = blockIdx.x >> 3, h = blockIdx.x & 7;
    for (int idx = tid; idx < 77 * 16; idx += 256) {
        int n = idx >> 4, dq = (idx & 15) * 4;
        *(float4*)&ks[n * NS + dq] =
            *(const float4*)&k[((size_t)b * 77 + n) * 512 + h * 64 + dq];
        *(float4*)&vs[n * NS + dq] =
            *(const float4*)&v[((size_t)b * 77 + n) * 512 + h * 64 + dq];
    }
    __syncthreads();
    const int e = tid & 63, dq = tid >> 6;
    float acc[16];
#pragma unroll
    for (int u = 0; u < 16; ++u) acc[u] = 0.f;
    for (int n = 0; n < 77; ++n) {
        float vv = vs[n * NS + e];
#pragma unroll
        for (int u4 = 0; u4 < 4; ++u4) {
            float4 kk = *(const float4*)&ks[n * NS + dq * 16 + u4 * 4];
            acc[u4 * 4 + 0] = fmaf(kk.x, vv, acc[u4 * 4 + 0]);
            acc[u4 * 4 + 1] = fmaf(kk.y, vv, acc[u4 * 4 + 1]);
            acc[u4 * 4 + 2] = fmaf(kk.z, vv, acc[u4 * 4 + 2]);
            acc[u4 * 4 + 3] = fmaf(kk.w, vv, acc[u4 * 4 + 3]);
        }
    }
    unsigned short ob[16];
#pragma unroll
    for (int u = 0; u < 16; ++u) ob[u] = f2bf(acc[u]);
    size_t base = (((size_t)b * 8 + h) * 64 + e) * 64 + dq * 16;
    *(uint4*)&attnT[base] = make_uint4(pk2(ob[0], ob[1]), pk2(ob[2], ob[3]),
                                       pk2(ob[4], ob[5]), pk2(ob[6], ob[7]));
    *(uint4*)&attnT[base + 8] = make_uint4(pk2(ob[8], ob[9]), pk2(ob[10], ob[11]),
                                           pk2(ob[12], ob[13]), pk2(ob[14], ob[15]));
}

// ---- FINAL: out[ib, c, t] = bf2f(resT[ib*512+t][c]) + sum_d q[b,t,c-head]*attnT
// one write per output element, no atomics (cidx is a permutation).
__global__ __launch_bounds__(256) void yattn_final(
        const unsigned short* __restrict__ q,
        const unsigned short* __restrict__ at,
        const unsigned short* __restrict__ resT,
        const int* __restrict__ cidx, float* __restrict__ out) {
    const int tid = threadIdx.x;
    const int lane = tid & 63, wv = tid >> 6;
    const int lq = lane & 15, qd = lane >> 4;
    const int t0 = blockIdx.x * 256 + wv * 64;
    const int h = blockIdx.y, b = blockIdx.z;
    const int ib = cidx[b];
    floatx4 acc[4][4];
#pragma unroll
    for (int i = 0; i < 4; ++i)
#pragma unroll
        for (int j = 0; j < 4; ++j) acc[i][j] = (floatx4){0.f, 0.f, 0.f, 0.f};
#pragma unroll
    for (int ks = 0; ks < 2; ++ks) {
        short8 av[4], bv[4];
#pragma unroll
        for (int i = 0; i < 4; ++i)
            av[i] = *(const short8*)
                &q[((size_t)(b * 512 + t0 + i * 16 + lq)) * 512 + h * 64 + ks * 32 + qd * 8];
#pragma unroll
        for (int j = 0; j < 4; ++j)
            bv[j] = *(const short8*)
                &at[(((size_t)(b * 8 + h)) * 64 + j * 16 + lq) * 64 + ks * 32 + qd * 8];
#pragma unroll
        for (int i = 0; i < 4; ++i)
#pragma unroll
            for (int j = 0; j < 4; ++j)
                acc[i][j] = __builtin_amdgcn_mfma_f32_16x16x32_bf16(
                    av[i], bv[j], acc[i][j], 0, 0, 0);
    }
    // D: row = t (qd*4+r within i*16), col = e (j*16+lq)
#pragma unroll
    for (int j = 0; j < 4; ++j) {
        int c = h * 64 + j * 16 + lq;
#pragma unroll
        for (int i = 0; i < 4; ++i) {
            int tb = t0 + i * 16 + qd * 4;
            float4 o;
            float vr[4];
#pragma unroll
            for (int r = 0; r < 4; ++r)
                vr[r] = acc[i][j][r] +
                        bf2f(resT[((size_t)(ib * 512 + tb + r)) * 512 + c]);
            o.x = vr[0]; o.y = vr[1]; o.z = vr[2]; o.w = vr[3];
            *(float4*)&out[((size_t)ib * 512 + c) * 512 + tb] = o;
        }
    }
}

extern "C" void kernel_launch(void* const* d_in, const int* in_sizes, int n_in,
                              void* d_out, int out_size, void* d_ws, size_t ws_size,
                              hipStream_t stream) {
    (void)in_sizes; (void)n_in; (void)out_size; (void)ws_size;
    const float* x       = (const float*)d_in[0];
    const float* t       = (const float*)d_in[1];
    const float* cond    = (const float*)d_in[2];
    const float* conv0_w = (const float*)d_in[3];
    const float* conv0_b = (const float*)d_in[4];
    const float* gn0_g   = (const float*)d_in[5];
    const float* gn0_b   = (const float*)d_in[6];
    const float* tm_w    = (const float*)d_in[7];
    const float* tm_b    = (const float*)d_in[8];
    const float* conv1_w = (const float*)d_in[9];
    const float* conv1_b = (const float*)d_in[10];
    const float* gn1_g   = (const float*)d_in[11];
    const float* gn1_b   = (const float*)d_in[12];
    const float* res_w   = (const float*)d_in[13];
    const float* res_b   = (const float*)d_in[14];
    const float* ln_x_g  = (const float*)d_in[15];
    const float* ln_x_b  = (const float*)d_in[16];
    const float* ln_c_g  = (const float*)d_in[17];
    const float* ln_c_b  = (const float*)d_in[18];
    const float* q_w     = (const float*)d_in[19];
    const float* q_b     = (const float*)d_in[20];
    const float* k_w     = (const float*)d_in[21];
    const float* k_b     = (const float*)d_in[22];
    const float* v_w     = (const float*)d_in[23];
    const float* v_b     = (const float*)d_in[24];
    const int*   cidx    = (const int*)d_in[25];
    float* out = (float*)d_out;

    char* WS = (char*)d_ws;
    unsigned short* xT    = (unsigned short*)(WS + 0);           // steps 4-8
    unsigned short* cnb   = (unsigned short*)(WS + 0);           // steps 12-14
    unsigned short* attnT = (unsigned short*)(WS + 8388608);     // 16-17
    unsigned short* h0T   = (unsigned short*)(WS + 16777216);    // 6-7
    unsigned short* xlnT  = (unsigned short*)(WS + 16777216);    // 10-11
    float*          kb    = (float*)(WS + 16777216);             // 13-16
    float*          vb    = (float*)(WS + 26869760);             // 14-16
    unsigned short* h1T   = (unsigned short*)(WS + 50331648);    // 7-8
    unsigned short* qbf   = (unsigned short*)(WS + 50331648);    // 11-17
    unsigned short* outTb = (unsigned short*)(WS + 83886080);    // 8-end
    unsigned short* wp0   = (unsigned short*)(WS + 83886080);    // 1-6 (dead before outTb)
    unsigned short* wp1   = (unsigned short*)(WS + 86507520);    // 2-7 (dead before outTb)
    unsigned short* wr    = (unsigned short*)(WS + 117440512);
    unsigned short* wq    = (unsigned short*)(WS + 117702656);
    unsigned short* wk    = (unsigned short*)(WS + 118226944);
    unsigned short* wvv   = (unsigned short*)(WS + 119013376);
    float*          ssb   = (float*)(WS + 119799808);
    float*          mt    = (float*)(WS + 120061952);

    pack_w<<<dim3((512*256*5)/256), dim3(256), 0, stream>>>(conv0_w, wp0, 256, 5, 512*256*5);
    pack_w<<<dim3((512*512*5)/256), dim3(256), 0, stream>>>(conv1_w, wp1, 512, 5, 512*512*5);
    cvt_bf16<<<dim3(128),  dim3(256), 0, stream>>>(res_w, wr, 32768);
    cvt_bf16<<<dim3(256),  dim3(256), 0, stream>>>(q_w,   wq, 65536);
    cvt_bf16<<<dim3(384),  dim3(256), 0, stream>>>(k_w,   wk, 98304);
    cvt_bf16<<<dim3(384),  dim3(256), 0, stream>>>(v_w,   wvv, 98304);
    xpose_cvt<<<dim3(8, 4, 64), dim3(256), 0, stream>>>(x, xT);
    mish_k<<<dim3(128), dim3(256), 0, stream>>>(t, mt, 32768);
    gemm_nt<512><<<dim3(1, 16), dim3(256), 0, stream>>>(mt, tm_w, tm_b, ssb, 64, 1024);
    conv5_mfma<256, true><<<dim3(2, 8, 64), dim3(256), 0, stream>>>(
        xT, wp0, conv0_b, gn0_g, gn0_b, ssb, h0T);
    conv5_mfma<512, false><<<dim3(2, 8, 64), dim3(256), 0, stream>>>(
        h0T, wp1, conv1_b, gn1_g, gn1_b, (const float*)nullptr, h1T);
    // res GEMM: outTb = bf16(res + h1), token-major only
    gemm1_mfma<256, 0><<<dim3(128, 8), dim3(256), 0, stream>>>(
        xT, wr, res_b, h1T, (float*)nullptr, outTb, 32768);
    lnrow<<<dim3(1024), dim3(256), 0, stream>>>(outTb, ln_x_g, ln_x_b, cidx, xlnT);
    gemm1_mfma<512, 1><<<dim3(128, 8), dim3(256), 0, stream>>>(
        xlnT, wq, q_b, (const unsigned short*)nullptr, (float*)nullptr, qbf, 32768);
    lnc_k<<<dim3(4928), dim3(256), 0, stream>>>(cond, ln_c_g, ln_c_b, cidx, cnb);
    gemm1_mfma<768, 2><<<dim3(20, 8), dim3(256), 0, stream>>>(
        cnb, wk, k_b, (const unsigned short*)nullptr, kb, (unsigned short*)nullptr, 4928);
    gemm1_mfma<768, 2><<<dim3(20, 8), dim3(256), 0, stream>>>(
        cnb, wvv, v_b, (const unsigned short*)nullptr, vb, (unsigned short*)nullptr, 4928);
    ksm_k<<<dim3(128), dim3(256), 0, stream>>>(kb);
    attn_k<<<dim3(512), dim3(256), 0, stream>>>(kb, vb, attnT);
    // FINAL: d_out = res+h1 (+ y), single coalesced write, no atomics
    yattn_final<<<dim3(2, 8, 64), dim3(256), 0, stream>>>(qbf, attnT, outTb, cidx, out);
}

// Round 5
// 612.548 us; speedup vs baseline: 5.7215x; 1.0635x over previous
//
#include <hip/hip_runtime.h>
#include <math.h>

#define EPS 1e-5f

typedef __attribute__((ext_vector_type(8))) short short8;
typedef __attribute__((ext_vector_type(4))) float floatx4;

typedef __attribute__((address_space(1))) const void* gas1_t;
typedef __attribute__((address_space(3))) void* las3_t;

__device__ __forceinline__ void glls16(const void* g, void* l) {
    __builtin_amdgcn_global_load_lds((gas1_t)g, (las3_t)l, 16, 0, 0);
}

__device__ __forceinline__ float mishf(float x) {
    float sp = fmaxf(x, 0.0f) + log1pf(expf(-fabsf(x)));
    return x * tanhf(sp);
}
__device__ __forceinline__ unsigned short f2bf(float f) {
    unsigned int u = __float_as_uint(f);
    unsigned int r = (u + 0x7fffu + ((u >> 16) & 1u)) >> 16;
    return (unsigned short)r;
}
__device__ __forceinline__ float bf2f(unsigned short s) {
    return __uint_as_float(((unsigned int)s) << 16);
}
__device__ __forceinline__ unsigned int pk2(unsigned short a, unsigned short b) {
    return (unsigned int)a | ((unsigned int)b << 16);
}

// ================= fused setup: weight packs, cvt, mish, zero pads ========
__global__ __launch_bounds__(256) void setup_k(
        const float* __restrict__ conv0_w, const float* __restrict__ conv1_w,
        const float* __restrict__ res_w, const float* __restrict__ q_w,
        const float* __restrict__ k_w, const float* __restrict__ v_w,
        const float* __restrict__ t,
        unsigned short* __restrict__ wp0, unsigned short* __restrict__ wp1,
        unsigned short* __restrict__ wr, unsigned short* __restrict__ wq,
        unsigned short* __restrict__ wk, unsigned short* __restrict__ wvv,
        float* __restrict__ mt,
        unsigned short* __restrict__ xTp, unsigned short* __restrict__ h0Tp) {
    const int blk = blockIdx.x, tid = threadIdx.x;
    if (blk < 2560) {                       // pack conv0_w -> wp0 [kk][co][ci]
        int o = blk * 256 + tid;
        int ci = o & 255, co = (o >> 8) & 511, kk = o >> 17;
        wp0[o] = f2bf(conv0_w[((size_t)co * 256 + ci) * 5 + kk]);
    } else if (blk < 7680) {                // pack conv1_w -> wp1
        int o = (blk - 2560) * 256 + tid;
        int ci = o & 511, co = (o >> 9) & 511, kk = o >> 18;
        wp1[o] = f2bf(conv1_w[((size_t)co * 512 + ci) * 5 + kk]);
    } else if (blk < 7808) {                // res_w cvt
        int i = (blk - 7680) * 256 + tid;
        float4 f = *(const float4*)&res_w[(size_t)i * 4];
        *(uint2*)&wr[(size_t)i * 4] =
            make_uint2(pk2(f2bf(f.x), f2bf(f.y)), pk2(f2bf(f.z), f2bf(f.w)));
    } else if (blk < 8064) {                // q_w cvt
        int i = (blk - 7808) * 256 + tid;
        float4 f = *(const float4*)&q_w[(size_t)i * 4];
        *(uint2*)&wq[(size_t)i * 4] =
            make_uint2(pk2(f2bf(f.x), f2bf(f.y)), pk2(f2bf(f.z), f2bf(f.w)));
    } else if (blk < 8448) {                // k_w cvt
        int i = (blk - 8064) * 256 + tid;
        float4 f = *(const float4*)&k_w[(size_t)i * 4];
        *(uint2*)&wk[(size_t)i * 4] =
            make_uint2(pk2(f2bf(f.x), f2bf(f.y)), pk2(f2bf(f.z), f2bf(f.w)));
    } else if (blk < 8832) {                // v_w cvt
        int i = (blk - 8448) * 256 + tid;
        float4 f = *(const float4*)&v_w[(size_t)i * 4];
        *(uint2*)&wvv[(size_t)i * 4] =
            make_uint2(pk2(f2bf(f.x), f2bf(f.y)), pk2(f2bf(f.z), f2bf(f.w)));
    } else if (blk < 8960) {                // mish(t)
        int i = (blk - 8832) * 256 + tid;
        mt[i] = mishf(t[i]);
    } else if (blk < 8992) {                // zero xTp pad rows
        int idx = (blk - 8960) * 256 + tid;     // 8192 uint4 stores
        int u = idx * 8;
        int c = u & 255, r4 = (u >> 8) & 3, b = u >> 10;
        int row = (r4 < 2) ? r4 : (512 + r4);
        *(uint4*)&xTp[((size_t)b * 516 + row) * 256 + c] = make_uint4(0, 0, 0, 0);
    } else {                                // zero h0Tp pad rows
        int idx = (blk - 8992) * 256 + tid;     // 16384 uint4 stores
        int u = idx * 8;
        int c = u & 511, r4 = (u >> 9) & 3, b = u >> 11;
        int row = (r4 < 2) ? r4 : (512 + r4);
        *(uint4*)&h0Tp[((size_t)b * 516 + row) * 512 + c] = make_uint4(0, 0, 0, 0);
    }
}

// ------------- x [b][ci][l] fp32 -> xTp [b][516][256] bf16 (rows 2..513)
__global__ __launch_bounds__(256) void xpose_cvt(const float* __restrict__ x,
        unsigned short* __restrict__ xT) {
    __shared__ float tile[64][68];
    const int tid = threadIdx.x;
    const int l0 = blockIdx.x * 64, c0 = blockIdx.y * 64, b = blockIdx.z;
    for (int idx = tid; idx < 64 * 16; idx += 256) {
        int cr = idx >> 4, lc = (idx & 15) * 4;
        float4 f = *(const float4*)&x[((size_t)b * 256 + c0 + cr) * 512 + l0 + lc];
        tile[cr][lc] = f.x; tile[cr][lc + 1] = f.y;
        tile[cr][lc + 2] = f.z; tile[cr][lc + 3] = f.w;
    }
    __syncthreads();
    for (int idx = tid; idx < 64 * 16; idx += 256) {
        int lr = idx >> 4, cc = (idx & 15) * 4;
        *(uint2*)&xT[((size_t)b * 516 + 2 + l0 + lr) * 256 + c0 + cc] =
            make_uint2(pk2(f2bf(tile[cc][lr]), f2bf(tile[cc + 1][lr])),
                       pk2(f2bf(tile[cc + 2][lr]), f2bf(tile[cc + 3][lr])));
    }
}

// ------------------------------------------- fp32 NT GEMM (ss only, tiny)
template<int KD>
__global__ __launch_bounds__(256) void gemm_nt(const float* __restrict__ A,
        const float* __restrict__ W, const float* __restrict__ bias,
        float* __restrict__ C, int M, int N) {
    constexpr int ST = 20;
    __shared__ __align__(16) float As[64 * ST];
    __shared__ __align__(16) float Ws[64 * ST];
    const int tid = threadIdx.x;
    const int r0 = blockIdx.x * 64, c0 = blockIdx.y * 64;
    const int tx = tid & 15, ty = tid >> 4;
    const int lrow = tid >> 2, lk = (tid & 3) * 4;
    float acc[4][4];
#pragma unroll
    for (int i = 0; i < 4; ++i)
#pragma unroll
        for (int j = 0; j < 4; ++j) acc[i][j] = 0.f;
    for (int k0 = 0; k0 < KD; k0 += 16) {
        __syncthreads();
        *(float4*)&As[lrow * ST + lk] =
            *(const float4*)&A[(size_t)(r0 + lrow) * KD + k0 + lk];
        *(float4*)&Ws[lrow * ST + lk] =
            *(const float4*)&W[(size_t)(c0 + lrow) * KD + k0 + lk];
        __syncthreads();
#pragma unroll
        for (int kk = 0; kk < 16; kk += 4) {
            float4 av[4], wv[4];
#pragma unroll
            for (int i = 0; i < 4; ++i)
                av[i] = *(const float4*)&As[(ty + 16 * i) * ST + kk];
#pragma unroll
            for (int j = 0; j < 4; ++j)
                wv[j] = *(const float4*)&Ws[(tx + 16 * j) * ST + kk];
#pragma unroll
            for (int i = 0; i < 4; ++i)
#pragma unroll
                for (int j = 0; j < 4; ++j) {
                    acc[i][j] = fmaf(av[i].x, wv[j].x, acc[i][j]);
                    acc[i][j] = fmaf(av[i].y, wv[j].y, acc[i][j]);
                    acc[i][j] = fmaf(av[i].z, wv[j].z, acc[i][j]);
                    acc[i][j] = fmaf(av[i].w, wv[j].w, acc[i][j]);
                }
        }
    }
#pragma unroll
    for (int j = 0; j < 4; ++j) {
        int c = c0 + tx + 16 * j;
        float bv = bias[c];
#pragma unroll
        for (int i = 0; i < 4; ++i)
            C[(size_t)(r0 + ty + 16 * i) * N + c] = acc[i][j] + bv;
    }
}

// ====== MFMA conv (KS=5), padded input, prefetch double-buffer, fused GN ===
// xb: [64][516][CI] bf16 (rows 0,1,514,515 zero); wp: [5][512][CI] bf16
// out: OPAD ? [64][516][512] (rows 2..513) : [64][512][512]
template<int CI, bool FILM, bool OPAD>
__global__ __launch_bounds__(256) void conv5_mfma(
        const unsigned short* __restrict__ xb,
        const unsigned short* __restrict__ wp,
        const float* __restrict__ bias,
        const float* __restrict__ gam, const float* __restrict__ bet,
        const float* __restrict__ ss,
        unsigned short* __restrict__ outT) {
    constexpr int NC = CI / 32;
    __shared__ __align__(16) unsigned short xs[2][260 * 32];
    __shared__ __align__(16) unsigned short wsm[2][5 * 64 * 32];
    __shared__ float sgam[64], sbet[64], sbias[64], sscale[64], sshift[64];

    const int tid = threadIdx.x;
    const int l0 = blockIdx.x * 256;
    const int co0 = blockIdx.y * 64;
    const int b = blockIdx.z;
    const int lane = tid & 63;
    const int wv = tid >> 6;
    const int lq = lane & 15, qd = lane >> 4;
    const int wn = wv * 64;

    if (tid < 64) {
        int co = co0 + tid;
        sbias[tid] = bias[co];
        sgam[tid] = gam[co];
        sbet[tid] = bet[co];
        if (FILM) {
            sscale[tid] = ss[(size_t)b * 1024 + co];
            sshift[tid] = ss[(size_t)b * 1024 + 512 + co];
        }
    }

    const unsigned short* gxb = xb + ((size_t)b * 516 + l0) * CI;
    const unsigned short* gwb = wp + (size_t)co0 * CI;

    auto stage = [&](int c, int buf) {
        const unsigned short* gx = gxb + c * 32;
        unsigned short* xd = (unsigned short*)xs[buf];
#pragma unroll
        for (int it = 0; it < 5; ++it) {
            int task = it * 256 + tid;
            if (task < 1040) {
                int ri = task >> 2, pos = task & 3;
                int seg = pos ^ ((ri >> 1) & 3);
                glls16(gx + (size_t)ri * CI + seg * 8, xd + (it * 256 + wn) * 8);
            }
        }
        const unsigned short* gw = gwb + c * 32;
        unsigned short* wd = (unsigned short*)wsm[buf];
#pragma unroll
        for (int it = 0; it < 5; ++it) {
            int task = it * 256 + tid;
            int kk = task >> 8, r = task & 255;
            int col = r >> 2, pos = r & 3;
            int seg = pos ^ ((col >> 1) & 3);
            glls16(gw + ((size_t)kk * 512 + col) * CI + seg * 8,
                   wd + (it * 256 + wn) * 8);
        }
    };

    floatx4 acc[4][4];
#pragma unroll
    for (int i = 0; i < 4; ++i)
#pragma unroll
        for (int j = 0; j < 4; ++j) acc[i][j] = (floatx4){0.f, 0.f, 0.f, 0.f};

    stage(0, 0);
    __syncthreads();
    for (int c = 0; c < NC; ++c) {
        if (c + 1 < NC) stage(c + 1, (c + 1) & 1);
        const unsigned short* xr = (const unsigned short*)xs[c & 1];
        const unsigned short* wr_ = (const unsigned short*)wsm[c & 1];
#pragma unroll
        for (int kk = 0; kk < 5; ++kk) {
            short8 bvf[4];
#pragma unroll
            for (int j = 0; j < 4; ++j) {
                int row = wn + j * 16 + lq + kk;
                int pos = qd ^ ((row >> 1) & 3);
                bvf[j] = *(const short8*)&xr[row * 32 + pos * 8];
            }
#pragma unroll
            for (int i = 0; i < 4; ++i) {
                int crow = i * 16 + lq;
                int pos = qd ^ ((crow >> 1) & 3);
                short8 av = *(const short8*)&wr_[kk * 2048 + crow * 32 + pos * 8];
#pragma unroll
                for (int j = 0; j < 4; ++j)
                    acc[i][j] = __builtin_amdgcn_mfma_f32_16x16x32_bf16(
                        av, bvf[j], acc[i][j], 0, 0, 0);
            }
        }
        __syncthreads();
    }
    // ---- fused epilogue: bias, GN stats over 64 co per l, FiLM, mish, bf16
    float m_[4], rs_[4];
#pragma unroll
    for (int j = 0; j < 4; ++j) {
        float s1 = 0.f, s2 = 0.f;
#pragma unroll
        for (int i = 0; i < 4; ++i) {
            float4 bv4 = *(const float4*)&sbias[i * 16 + qd * 4];
            float ba[4] = {bv4.x, bv4.y, bv4.z, bv4.w};
#pragma unroll
            for (int r = 0; r < 4; ++r) {
                float v = acc[i][j][r] + ba[r];
                acc[i][j][r] = v;
                s1 += v; s2 += v * v;
            }
        }
        s1 += __shfl_xor(s1, 16, 64); s2 += __shfl_xor(s2, 16, 64);
        s1 += __shfl_xor(s1, 32, 64); s2 += __shfl_xor(s2, 32, 64);
        float mean = s1 * (1.f / 64.f);
        float var = s2 * (1.f / 64.f) - mean * mean;
        m_[j] = mean; rs_[j] = rsqrtf(var + EPS);
    }
#pragma unroll
    for (int j = 0; j < 4; ++j) {
        int l = l0 + wn + j * 16 + lq;
        size_t rowbase = OPAD ? (((size_t)b * 516 + 2 + l) * 512 + co0)
                              : (((size_t)b * 512 + l) * 512 + co0);
#pragma unroll
        for (int i = 0; i < 4; ++i) {
            float4 g4 = *(const float4*)&sgam[i * 16 + qd * 4];
            float4 b4 = *(const float4*)&sbet[i * 16 + qd * 4];
            float ga[4] = {g4.x, g4.y, g4.z, g4.w};
            float be[4] = {b4.x, b4.y, b4.z, b4.w};
            float sa[4] = {0, 0, 0, 0}, sh[4] = {0, 0, 0, 0};
            if (FILM) {
                float4 s4 = *(const float4*)&sscale[i * 16 + qd * 4];
                float4 h4 = *(const float4*)&sshift[i * 16 + qd * 4];
                sa[0] = s4.x; sa[1] = s4.y; sa[2] = s4.z; sa[3] = s4.w;
                sh[0] = h4.x; sh[1] = h4.y; sh[2] = h4.z; sh[3] = h4.w;
            }
            unsigned short o[4];
#pragma unroll
            for (int r = 0; r < 4; ++r) {
                float v = (acc[i][j][r] - m_[j]) * rs_[j] * ga[r] + be[r];
                if (FILM) v = v * (1.f + sa[r]) + sh[r];
                o[r] = f2bf(mishf(v));
            }
            *(uint2*)&outT[rowbase + i * 16 + qd * 4] =
                make_uint2(pk2(o[0], o[1]), pk2(o[2], o[3]));
        }
    }
}

// ====== generic MFMA GEMM, prefetch double-buffer =========================
// EPI 0=RES(add h1T dense, write outTb bf16); 1=QSM(softmax/head); 2=KV fp32
// PADA: A rows live in [b][516][KD] at row 2+t
template<int KD, int EPI, bool PADA>
__global__ __launch_bounds__(256) void gemm1_mfma(
        const unsigned short* __restrict__ A,
        const unsigned short* __restrict__ W,
        const float* __restrict__ bias,
        const unsigned short* __restrict__ addT,
        float* __restrict__ outF,
        unsigned short* __restrict__ outB,
        int Mreal) {
    constexpr int NC = KD / 32;
    __shared__ __align__(16) unsigned short xs[2][256 * 32];
    __shared__ __align__(16) unsigned short wsm[2][64 * 32];
    __shared__ float sbias[64];
    const int tid = threadIdx.x;
    const int m0 = blockIdx.x * 256;
    const int n0 = blockIdx.y * 64;
    const int lane = tid & 63;
    const int wv = tid >> 6;
    const int lq = lane & 15, qd = lane >> 4;
    const int wn = wv * 64;
    if (tid < 64) sbias[tid] = bias[n0 + tid];

    const size_t arow0 = PADA ? ((size_t)(m0 >> 9) * 516 + 2 + (m0 & 511))
                              : (size_t)m0;
    const unsigned short* gA = A + arow0 * KD;
    const unsigned short* gW = W + (size_t)n0 * KD;

    auto stage = [&](int c, int buf) {
        const unsigned short* gx = gA + c * 32;
        unsigned short* xd = (unsigned short*)xs[buf];
#pragma unroll
        for (int it = 0; it < 4; ++it) {
            int task = it * 256 + tid;
            int ri = task >> 2, pos = task & 3;
            int seg = pos ^ ((ri >> 1) & 3);
            glls16(gx + (size_t)ri * KD + seg * 8, xd + (it * 256 + wn) * 8);
        }
        const unsigned short* gw = gW + c * 32;
        unsigned short* wd = (unsigned short*)wsm[buf];
        {
            int col = tid >> 2, pos = tid & 3;
            int seg = pos ^ ((col >> 1) & 3);
            glls16(gw + (size_t)col * KD + seg * 8, wd + wn * 8);
        }
    };

    floatx4 acc[4][4];
#pragma unroll
    for (int i = 0; i < 4; ++i)
#pragma unroll
        for (int j = 0; j < 4; ++j) acc[i][j] = (floatx4){0.f, 0.f, 0.f, 0.f};

    stage(0, 0);
    __syncthreads();
    for (int c = 0; c < NC; ++c) {
        if (c + 1 < NC) stage(c + 1, (c + 1) & 1);
        const unsigned short* xr = (const unsigned short*)xs[c & 1];
        const unsigned short* wr_ = (const unsigned short*)wsm[c & 1];
        short8 bvf[4];
#pragma unroll
        for (int j = 0; j < 4; ++j) {
            int row = wn + j * 16 + lq;
            int pos = qd ^ ((row >> 1) & 3);
            bvf[j] = *(const short8*)&xr[row * 32 + pos * 8];
        }
#pragma unroll
        for (int i = 0; i < 4; ++i) {
            int crow = i * 16 + lq;
            int pos = qd ^ ((crow >> 1) & 3);
            short8 av = *(const short8*)&wr_[crow * 32 + pos * 8];
#pragma unroll
            for (int j = 0; j < 4; ++j)
                acc[i][j] = __builtin_amdgcn_mfma_f32_16x16x32_bf16(
                    av, bvf[j], acc[i][j], 0, 0, 0);
        }
        __syncthreads();
    }
#pragma unroll
    for (int i = 0; i < 4; ++i) {
        float4 bv4 = *(const float4*)&sbias[i * 16 + qd * 4];
        float ba[4] = {bv4.x, bv4.y, bv4.z, bv4.w};
#pragma unroll
        for (int j = 0; j < 4; ++j)
#pragma unroll
            for (int r = 0; r < 4; ++r) acc[i][j][r] += ba[r];
    }
    if (EPI == 0) {  // RES
#pragma unroll
        for (int j = 0; j < 4; ++j) {
            int m = m0 + wn + j * 16 + lq;
#pragma unroll
            for (int i = 0; i < 4; ++i) {
                int n = n0 + i * 16 + qd * 4;
                uint2 hv = *(const uint2*)&addT[(size_t)m * 512 + n];
                float vr[4];
                vr[0] = acc[i][j][0] + bf2f((unsigned short)(hv.x & 0xffff));
                vr[1] = acc[i][j][1] + bf2f((unsigned short)(hv.x >> 16));
                vr[2] = acc[i][j][2] + bf2f((unsigned short)(hv.y & 0xffff));
                vr[3] = acc[i][j][3] + bf2f((unsigned short)(hv.y >> 16));
                *(uint2*)&outB[(size_t)m * 512 + n] =
                    make_uint2(pk2(f2bf(vr[0]), f2bf(vr[1])),
                               pk2(f2bf(vr[2]), f2bf(vr[3])));
            }
        }
    } else if (EPI == 1) {  // QSM
#pragma unroll
        for (int j = 0; j < 4; ++j) {
            float mx = -3.4e38f;
#pragma unroll
            for (int i = 0; i < 4; ++i)
#pragma unroll
                for (int r = 0; r < 4; ++r) mx = fmaxf(mx, acc[i][j][r]);
            mx = fmaxf(mx, __shfl_xor(mx, 16, 64));
            mx = fmaxf(mx, __shfl_xor(mx, 32, 64));
            float s = 0.f;
#pragma unroll
            for (int i = 0; i < 4; ++i)
#pragma unroll
                for (int r = 0; r < 4; ++r) {
                    float e = expf(acc[i][j][r] - mx);
                    acc[i][j][r] = e; s += e;
                }
            s += __shfl_xor(s, 16, 64);
            s += __shfl_xor(s, 32, 64);
            float inv = 1.f / s;
            int m = m0 + wn + j * 16 + lq;
#pragma unroll
            for (int i = 0; i < 4; ++i) {
                *(uint2*)&outB[(size_t)m * 512 + n0 + i * 16 + qd * 4] =
                    make_uint2(pk2(f2bf(acc[i][j][0] * inv), f2bf(acc[i][j][1] * inv)),
                               pk2(f2bf(acc[i][j][2] * inv), f2bf(acc[i][j][3] * inv)));
            }
        }
    } else {  // KV
#pragma unroll
        for (int j = 0; j < 4; ++j) {
            int m = m0 + wn + j * 16 + lq;
            if (m < Mreal) {
#pragma unroll
                for (int i = 0; i < 4; ++i) {
                    float4 o = {acc[i][j][0], acc[i][j][1], acc[i][j][2], acc[i][j][3]};
                    *(float4*)&outF[(size_t)m * 512 + n0 + i * 16 + qd * 4] = o;
                }
            }
        }
    }
}

// ---------- row LayerNorm of outTb[cidx[b]] (512 bf16) -> xlnT bf16
__global__ __launch_bounds__(256) void lnrow(const unsigned short* __restrict__ src,
        const float* __restrict__ g, const float* __restrict__ be,
        const int* __restrict__ cidx, unsigned short* __restrict__ dst) {
    const int tid = threadIdx.x;
    const int lane = tid & 63, wv = tid >> 6;
    const int row0 = blockIdx.x * 32 + wv * 8;
    for (int rr = 0; rr < 8; ++rr) {
        int m = row0 + rr;
        int b = m >> 9, t = m & 511;
        int ib = cidx[b];
        const unsigned short* sp = &src[((size_t)ib * 512 + t) * 512 + lane * 8];
        short8 u = *(const short8*)sp;
        float v[8];
        float s1 = 0.f, s2 = 0.f;
#pragma unroll
        for (int k = 0; k < 8; ++k) {
            v[k] = bf2f(((const unsigned short*)&u)[k]);
            s1 += v[k]; s2 += v[k] * v[k];
        }
#pragma unroll
        for (int o = 32; o > 0; o >>= 1) {
            s1 += __shfl_xor(s1, o, 64);
            s2 += __shfl_xor(s2, o, 64);
        }
        float mean = s1 * (1.f / 512.f);
        float var = s2 * (1.f / 512.f) - mean * mean;
        float rs = rsqrtf(var + EPS);
        float4 g0 = *(const float4*)&g[lane * 8];
        float4 g1 = *(const float4*)&g[lane * 8 + 4];
        float4 b0 = *(const float4*)&be[lane * 8];
        float4 b1 = *(const float4*)&be[lane * 8 + 4];
        float ga[8] = {g0.x, g0.y, g0.z, g0.w, g1.x, g1.y, g1.z, g1.w};
        float ba[8] = {b0.x, b0.y, b0.z, b0.w, b1.x, b1.y, b1.z, b1.w};
        unsigned short o8[8];
#pragma unroll
        for (int k = 0; k < 8; ++k)
            o8[k] = f2bf((v[k] - mean) * rs * ga[k] + ba[k]);
        *(uint4*)&dst[(size_t)m * 512 + lane * 8] =
            make_uint4(pk2(o8[0], o8[1]), pk2(o8[2], o8[3]),
                       pk2(o8[4], o8[5]), pk2(o8[6], o8[7]));
    }
}

// --------------------------- LayerNorm of cond rows (768) -> cnb bf16
__global__ __launch_bounds__(256) void lnc_k(const float* __restrict__ cond,
        const float* __restrict__ g, const float* __restrict__ be,
        const int* __restrict__ cidx, unsigned short* __restrict__ cn) {
    const int tid = threadIdx.x;
    const int bn = blockIdx.x;
    const int b = bn / 77, n = bn - b * 77;
    const int ib = cidx[b];
    const float* src = cond + ((size_t)ib * 77 + n) * 768;
    float v[3];
    float s = 0.f, s2 = 0.f;
#pragma unroll
    for (int i = 0; i < 3; ++i) {
        v[i] = src[tid + i * 256];
        s += v[i]; s2 += v[i] * v[i];
    }
#pragma unroll
    for (int o = 32; o > 0; o >>= 1) {
        s += __shfl_xor(s, o, 64);
        s2 += __shfl_xor(s2, o, 64);
    }
    __shared__ float r1[4], r2[4], mv[2];
    if ((tid & 63) == 0) { r1[tid >> 6] = s; r2[tid >> 6] = s2; }
    __syncthreads();
    if (tid == 0) {
        float ts = r1[0] + r1[1] + r1[2] + r1[3];
        float ts2 = r2[0] + r2[1] + r2[2] + r2[3];
        float m = ts * (1.f / 768.f);
        float var = ts2 * (1.f / 768.f) - m * m;
        mv[0] = m; mv[1] = rsqrtf(var + EPS);
    }
    __syncthreads();
    float m = mv[0], rs = mv[1];
    unsigned short* dst = cn + ((size_t)b * 77 + n) * 768;
#pragma unroll
    for (int i = 0; i < 3; ++i) {
        int c = tid + i * 256;
        dst[c] = f2bf((v[i] - m) * rs * g[c] + be[c]);
    }
}

// --- attnT[b,h,e,d] = sum_n ksm(k)[b,n,h*64+d] * v[b,n,h*64+e], k-softmax fused
__global__ __launch_bounds__(256) void attn_k(const float* __restrict__ k,
        const float* __restrict__ v, unsigned short* __restrict__ attnT) {
    constexpr int NS = 68;
    __shared__ __align__(16) float ks[77 * NS];
    __shared__ __align__(16) float vs[77 * NS];
    __shared__ float red[2][256];
    const int tid = threadIdx.x;
    const int b = blockIdx.x >> 3, h = blockIdx.x & 7;
    for (int idx = tid; idx < 77 * 16; idx += 256) {
        int n = idx >> 4, dq2 = (idx & 15) * 4;
        *(float4*)&ks[n * NS + dq2] =
            *(const float4*)&k[((size_t)b * 77 + n) * 512 + h * 64 + dq2];
        *(float4*)&vs[n * NS + dq2] =
            *(const float4*)&v[((size_t)b * 77 + n) * 512 + h * 64 + dq2];
    }
    __syncthreads();
    // fused k-softmax over n per d column (d = tid&63, 4 threads/column)
    {
        const int d = tid & 63, grp = tid >> 6;
        float mx = -3.4e38f;
        for (int n = grp; n < 77; n += 4) mx = fmaxf(mx, ks[n * NS + d]);
        red[0][grp * 64 + d] = mx;
        __syncthreads();
        mx = fmaxf(fmaxf(red[0][d], red[0][64 + d]),
                   fmaxf(red[0][128 + d], red[0][192 + d]));
        float s = 0.f;
        for (int n = grp; n < 77; n += 4) {
            float e = expf(ks[n * NS + d] - mx);
            ks[n * NS + d] = e; s += e;
        }
        red[1][grp * 64 + d] = s;
        __syncthreads();
        float inv = 1.f / (red[1][d] + red[1][64 + d] + red[1][128 + d] + red[1][192 + d]);
        for (int n = grp; n < 77; n += 4) ks[n * NS + d] *= inv;
    }
    __syncthreads();
    const int e = tid & 63, dq = tid >> 6;
    float acc[16];
#pragma unroll
    for (int u = 0; u < 16; ++u) acc[u] = 0.f;
    for (int n = 0; n < 77; ++n) {
        float vv = vs[n * NS + e];
#pragma unroll
        for (int u4 = 0; u4 < 4; ++u4) {
            float4 kk = *(const float4*)&ks[n * NS + dq * 16 + u4 * 4];
            acc[u4 * 4 + 0] = fmaf(kk.x, vv, acc[u4 * 4 + 0]);
            acc[u4 * 4 + 1] = fmaf(kk.y, vv, acc[u4 * 4 + 1]);
            acc[u4 * 4 + 2] = fmaf(kk.z, vv, acc[u4 * 4 + 2]);
            acc[u4 * 4 + 3] = fmaf(kk.w, vv, acc[u4 * 4 + 3]);
        }
    }
    unsigned short ob[16];
#pragma unroll
    for (int u = 0; u < 16; ++u) ob[u] = f2bf(acc[u]);
    size_t base = (((size_t)b * 8 + h) * 64 + e) * 64 + dq * 16;
    *(uint4*)&attnT[base] = make_uint4(pk2(ob[0], ob[1]), pk2(ob[2], ob[3]),
                                       pk2(ob[4], ob[5]), pk2(ob[6], ob[7]));
    *(uint4*)&attnT[base + 8] = make_uint4(pk2(ob[8], ob[9]), pk2(ob[10], ob[11]),
                                           pk2(ob[12], ob[13]), pk2(ob[14], ob[15]));
}

// ---- FINAL: out[ib, c, t] = bf2f(resT[..]) + (q @ attnT); no atomics
__global__ __launch_bounds__(256) void yattn_final(
        const unsigned short* __restrict__ q,
        const unsigned short* __restrict__ at,
        const unsigned short* __restrict__ resT,
        const int* __restrict__ cidx, float* __restrict__ out) {
    const int tid = threadIdx.x;
    const int lane = tid & 63, wv = tid >> 6;
    const int lq = lane & 15, qd = lane >> 4;
    const int t0 = blockIdx.x * 256 + wv * 64;
    const int h = blockIdx.y, b = blockIdx.z;
    const int ib = cidx[b];
    floatx4 acc[4][4];
#pragma unroll
    for (int i = 0; i < 4; ++i)
#pragma unroll
        for (int j = 0; j < 4; ++j) acc[i][j] = (floatx4){0.f, 0.f, 0.f, 0.f};
#pragma unroll
    for (int ks = 0; ks < 2; ++ks) {
        short8 av[4], bv[4];
#pragma unroll
        for (int i = 0; i < 4; ++i)
            av[i] = *(const short8*)
                &q[((size_t)(b * 512 + t0 + i * 16 + lq)) * 512 + h * 64 + ks * 32 + qd * 8];
#pragma unroll
        for (int j = 0; j < 4; ++j)
            bv[j] = *(const short8*)
                &at[(((size_t)(b * 8 + h)) * 64 + j * 16 + lq) * 64 + ks * 32 + qd * 8];
#pragma unroll
        for (int i = 0; i < 4; ++i)
#pragma unroll
            for (int j = 0; j < 4; ++j)
                acc[i][j] = __builtin_amdgcn_mfma_f32_16x16x32_bf16(
                    av[i], bv[j], acc[i][j], 0, 0, 0);
    }
#pragma unroll
    for (int j = 0; j < 4; ++j) {
        int c = h * 64 + j * 16 + lq;
#pragma unroll
        for (int i = 0; i < 4; ++i) {
            int tb = t0 + i * 16 + qd * 4;
            float vr[4];
#pragma unroll
            for (int r = 0; r < 4; ++r)
                vr[r] = acc[i][j][r] +
                        bf2f(resT[((size_t)(ib * 512 + tb + r)) * 512 + c]);
            float4 o = {vr[0], vr[1], vr[2], vr[3]};
            *(float4*)&out[((size_t)ib * 512 + c) * 512 + tb] = o;
        }
    }
}

extern "C" void kernel_launch(void* const* d_in, const int* in_sizes, int n_in,
                              void* d_out, int out_size, void* d_ws, size_t ws_size,
                              hipStream_t stream) {
    (void)in_sizes; (void)n_in; (void)out_size; (void)ws_size;
    const float* x       = (const float*)d_in[0];
    const float* t       = (const float*)d_in[1];
    const float* cond    = (const float*)d_in[2];
    const float* conv0_w = (const float*)d_in[3];
    const float* conv0_b = (const float*)d_in[4];
    const float* gn0_g   = (const float*)d_in[5];
    const float* gn0_b   = (const float*)d_in[6];
    const float* tm_w    = (const float*)d_in[7];
    const float* tm_b    = (const float*)d_in[8];
    const float* conv1_w = (const float*)d_in[9];
    const float* conv1_b = (const float*)d_in[10];
    const float* gn1_g   = (const float*)d_in[11];
    const float* gn1_b   = (const float*)d_in[12];
    const float* res_w   = (const float*)d_in[13];
    const float* res_b   = (const float*)d_in[14];
    const float* ln_x_g  = (const float*)d_in[15];
    const float* ln_x_b  = (const float*)d_in[16];
    const float* ln_c_g  = (const float*)d_in[17];
    const float* ln_c_b  = (const float*)d_in[18];
    const float* q_w     = (const float*)d_in[19];
    const float* q_b     = (const float*)d_in[20];
    const float* k_w     = (const float*)d_in[21];
    const float* k_b     = (const float*)d_in[22];
    const float* v_w     = (const float*)d_in[23];
    const float* v_b     = (const float*)d_in[24];
    const int*   cidx    = (const int*)d_in[25];
    float* out = (float*)d_out;

    char* WS = (char*)d_ws;
    // overlays; high-water 124.5 MB (134.6 MB proven in R1)
    unsigned short* xTp   = (unsigned short*)(WS + 0);          // [64][516][256]
    unsigned short* cnb   = (unsigned short*)(WS + 0);          // after res gemm
    unsigned short* attnT = (unsigned short*)(WS + 8388608);
    unsigned short* h0Tp  = (unsigned short*)(WS + 16908288);   // [64][516][512]
    unsigned short* xlnT  = (unsigned short*)(WS + 16908288);   // after conv1
    float*          kb    = (float*)(WS + 16908288);            // after q gemm
    float*          vb    = (float*)(WS + 27000832);
    unsigned short* h1T   = (unsigned short*)(WS + 50724864);   // [64][512][512]
    unsigned short* qbf   = (unsigned short*)(WS + 50724864);   // after res gemm
    unsigned short* outTb = (unsigned short*)(WS + 84279296);
    unsigned short* wp0   = (unsigned short*)(WS + 117833728);
    unsigned short* wp1   = (unsigned short*)(WS + 119144448);
    unsigned short* wr    = (unsigned short*)(WS + 121765888);
    unsigned short* wq    = (unsigned short*)(WS + 122028032);
    unsigned short* wk    = (unsigned short*)(WS + 122552320);
    unsigned short* wvv   = (unsigned short*)(WS + 123338752);
    float*          ssb   = (float*)(WS + 124125184);
    float*          mt    = (float*)(WS + 124387328);

    setup_k<<<dim3(9056), dim3(256), 0, stream>>>(
        conv0_w, conv1_w, res_w, q_w, k_w, v_w, t,
        wp0, wp1, wr, wq, wk, wvv, mt, xTp, h0Tp);
    xpose_cvt<<<dim3(8, 4, 64), dim3(256), 0, stream>>>(x, xTp);
    gemm_nt<512><<<dim3(1, 16), dim3(256), 0, stream>>>(mt, tm_w, tm_b, ssb, 64, 1024);
    conv5_mfma<256, true, true><<<dim3(2, 8, 64), dim3(256), 0, stream>>>(
        xTp, wp0, conv0_b, gn0_g, gn0_b, ssb, h0Tp);
    conv5_mfma<512, false, false><<<dim3(2, 8, 64), dim3(256), 0, stream>>>(
        h0Tp, wp1, conv1_b, gn1_g, gn1_b, (const float*)nullptr, h1T);
    gemm1_mfma<256, 0, true><<<dim3(128, 8), dim3(256), 0, stream>>>(
        xTp, wr, res_b, h1T, (float*)nullptr, outTb, 32768);
    lnrow<<<dim3(1024), dim3(256), 0, stream>>>(outTb, ln_x_g, ln_x_b, cidx, xlnT);
    gemm1_mfma<512, 1, false><<<dim3(128, 8), dim3(256), 0, stream>>>(
        xlnT, wq, q_b, (const unsigned short*)nullptr, (float*)nullptr, qbf, 32768);
    lnc_k<<<dim3(4928), dim3(256), 0, stream>>>(cond, ln_c_g, ln_c_b, cidx, cnb);
    gemm1_mfma<768, 2, false><<<dim3(20, 8), dim3(256), 0, stream>>>(
        cnb, wk, k_b, (const unsigned short*)nullptr, kb, (unsigned short*)nullptr, 4928);
    gemm1_mfma<768, 2, false><<<dim3(20, 8), dim3(256), 0, stream>>>(
        cnb, wvv, v_b, (const unsigned short*)nullptr, vb, (unsigned short*)nullptr, 4928);
    attn_k<<<dim3(512), dim3(256), 0, stream>>>(kb, vb, attnT);
    yattn_final<<<dim3(2, 8, 64), dim3(256), 0, stream>>>(qbf, attnT, outTb, cidx, out);
}